// Round 6
// baseline (291.628 us; speedup 1.0000x reference)
//
#include <hip/hip_runtime.h>

// Problem constants: D=512, H=8 (hd=64), DFF=2048, NE=64, ND=64, B=16
// Identities exploited (carried from prior rounds):
//  - dc cross-attention has softmax over 1 key -> t[j,b] = Wo(Wv f_n[j,b]+bv)+bo
//  - G_fj[j,i,b] = dec[i,b] + t[j,b]  (rank-decomposed; never materialized)
//  - LN(G_fj) linearity: K/V projections & pooling energy decompose into
//    per-i and per-j 1024-row GEMMs + scalar stats m[j,i,b], r[j,i,b].
// R15: barrier-amortization. ~260us is in-kernel (gaps ~2-3us each); 64x64
// tile = only 32 MFMA between barrier pairs (1:1 MFMA:ds_read). New
// BM=128xBN=64 tile (NW=8, wave-tile 32x32): 64 MFMA/block/K-step, applied
// to L2 (5 jobs + casts, thread-count-generalized), L6 (QKV fold), L9 (FFN1
// fold). K-order per output element unchanged -> bit-identical.

typedef __bf16 bf16_t;
typedef bf16_t bf16x8 __attribute__((ext_vector_type(8)));
typedef float f32x4 __attribute__((ext_vector_type(4)));
typedef unsigned short u16x4 __attribute__((ext_vector_type(4)));
typedef unsigned short u16x8 __attribute__((ext_vector_type(8)));

__device__ inline unsigned short f2bf(float f) {
  unsigned int u = __float_as_uint(f);
  u += 0x7fffu + ((u >> 16) & 1u);  // RNE
  return (unsigned short)(u >> 16);
}
__device__ inline float bf2f(unsigned short u) {
  return __uint_as_float(((unsigned int)u) << 16);
}

__device__ inline float wsum(float v) {
#pragma unroll
  for (int o = 1; o < 64; o <<= 1) v += __shfl_xor(v, o);
  return v;
}
__device__ inline float wmax(float v) {
#pragma unroll
  for (int o = 1; o < 64; o <<= 1) v = fmaxf(v, __shfl_xor(v, o));
  return v;
}

struct CastJob {
  const float* src;
  unsigned short* dst;
  int n;
  const float* cs;  // per-(i & 511) scale or null
};
struct CastPage {
  const float* src;
  unsigned short* dst;
};

// ---------------- LN / stats bodies ----------------------------------------
__device__ inline void ln_body(const float* __restrict__ x,
                               const float* __restrict__ g,
                               const float* __restrict__ be,
                               unsigned short* __restrict__ y, int t) {
  float v0 = x[t], v1 = x[t + 256];
  float s = wsum(v0 + v1);
  float s2 = wsum(v0 * v0 + v1 * v1);
  __shared__ float sh[8];
  int w = t >> 6, lane = t & 63;
  if (lane == 0) { sh[w] = s; sh[4 + w] = s2; }
  __syncthreads();
  s = sh[0] + sh[1] + sh[2] + sh[3];
  s2 = sh[4] + sh[5] + sh[6] + sh[7];
  float mean = s * (1.f / 512.f);
  float var = s2 * (1.f / 512.f) - mean * mean;
  float r = rsqrtf(var + 1e-5f);
  y[t] = f2bf((v0 - mean) * r * g[t] + be[t]);
  y[t + 256] = f2bf((v1 - mean) * r * g[t + 256] + be[t + 256]);
}

__device__ inline void stats_body(const float* __restrict__ x,
                                  float* __restrict__ m, float* __restrict__ q2,
                                  unsigned short* __restrict__ xb, int t,
                                  int row) {
  float v0 = x[t], v1 = x[t + 256];
  if (xb) {
    xb[t] = f2bf(v0);
    xb[t + 256] = f2bf(v1);
  }
  float s = wsum(v0 + v1);
  float s2 = wsum(v0 * v0 + v1 * v1);
  __shared__ float sh2[8];
  int w = t >> 6, lane = t & 63;
  if (lane == 0) { sh2[w] = s; sh2[4 + w] = s2; }
  __syncthreads();
  if (t == 0) {
    s = sh2[0] + sh2[1] + sh2[2] + sh2[3];
    s2 = sh2[4] + sh2[5] + sh2[6] + sh2[7];
    m[row] = s * (1.f / 512.f);
    q2[row] = s2 * (1.f / 512.f);
  }
}

// ------- phase0: Wf GEMM + LN(enc)+dec stats + casts + uvec(+bf) + zero -----
struct Phase0Args {
  const float* enc; const float* g_ec; const float* b_ec; unsigned short* f_n;
  const float* dec; float* md; float* q2d; unsigned short* dec_b;
  CastJob cast[4];
  const float* Wk; const float* Wv; const float* bk; const float* bv;
  const float* g_dci; const float* b_dci;
  float* u_k; float* u_v; float* c_k; float* c_v;
  // Wf = WoA @ WvA (512x512x512), bf = WoA @ bv2 + bo2
  const float* WoA; const float* WvA; unsigned short* Wfb;
  const float* bv2; const float* bo2; float* bf_out;
  float* zbase; int zcount;
};

__global__ __launch_bounds__(256) void phase0(Phase0Args a) {
  __shared__ unsigned short WAs[64][72];
  __shared__ unsigned short WBs[64][72];
  int bx = blockIdx.x;
  const int t = threadIdx.x;
  if (bx < 64) {
    // Wf[n,k] = sum_m Wo[n,m] * Wv[m,k]  (bf16 MFMA, fp32 staged+cast)
    const int bm = (bx >> 3) * 64;   // n rows
    const int bn = (bx & 7) * 64;    // k cols
    const int lane = t & 63;
    const int wave = t >> 6;
    const int wr = wave >> 1;
    const int wc = wave & 1;
    const int fr = lane & 15;
    const int fg = lane >> 4;
    const int rr = t >> 2;
    const int c = (t & 3) * 16;
    f32x4 acc[2][2] = {};
    for (int m0 = 0; m0 < 512; m0 += 64) {
      const float* ap = a.WoA + (size_t)(bm + rr) * 512 + m0 + c;
      float4 a0 = *(const float4*)ap;
      float4 a1 = *(const float4*)(ap + 4);
      float4 a2 = *(const float4*)(ap + 8);
      float4 a3 = *(const float4*)(ap + 12);
      u16x8 lo = {f2bf(a0.x), f2bf(a0.y), f2bf(a0.z), f2bf(a0.w),
                  f2bf(a1.x), f2bf(a1.y), f2bf(a1.z), f2bf(a1.w)};
      u16x8 hi = {f2bf(a2.x), f2bf(a2.y), f2bf(a2.z), f2bf(a2.w),
                  f2bf(a3.x), f2bf(a3.y), f2bf(a3.z), f2bf(a3.w)};
      *(u16x8*)&WAs[rr][c] = lo;
      *(u16x8*)&WAs[rr][c + 8] = hi;
      const float* bp = a.WvA + (size_t)(m0 + rr) * 512 + bn + c;
      float4 b0 = *(const float4*)bp;
      float4 b1 = *(const float4*)(bp + 4);
      float4 b2 = *(const float4*)(bp + 8);
      float4 b3 = *(const float4*)(bp + 12);
      float bv16[16] = {b0.x, b0.y, b0.z, b0.w, b1.x, b1.y, b1.z, b1.w,
                        b2.x, b2.y, b2.z, b2.w, b3.x, b3.y, b3.z, b3.w};
#pragma unroll
      for (int jj = 0; jj < 16; ++jj) WBs[c + jj][rr] = f2bf(bv16[jj]);
      __syncthreads();
#pragma unroll
      for (int ks = 0; ks < 2; ++ks) {
        int kk = ks * 32 + fg * 8;
        bf16x8 fa0 = *(const bf16x8*)&WAs[wr * 32 + fr][kk];
        bf16x8 fa1 = *(const bf16x8*)&WAs[wr * 32 + 16 + fr][kk];
        bf16x8 fb0 = *(const bf16x8*)&WBs[wc * 32 + fr][kk];
        bf16x8 fb1 = *(const bf16x8*)&WBs[wc * 32 + 16 + fr][kk];
        acc[0][0] = __builtin_amdgcn_mfma_f32_16x16x32_bf16(fa0, fb0, acc[0][0], 0, 0, 0);
        acc[0][1] = __builtin_amdgcn_mfma_f32_16x16x32_bf16(fa0, fb1, acc[0][1], 0, 0, 0);
        acc[1][0] = __builtin_amdgcn_mfma_f32_16x16x32_bf16(fa1, fb0, acc[1][0], 0, 0, 0);
        acc[1][1] = __builtin_amdgcn_mfma_f32_16x16x32_bf16(fa1, fb1, acc[1][1], 0, 0, 0);
      }
      __syncthreads();
    }
#pragma unroll
    for (int mt = 0; mt < 2; ++mt) {
#pragma unroll
      for (int nt = 0; nt < 2; ++nt) {
        int col = bn + wc * 32 + nt * 16 + fr;
        int rowb = bm + wr * 32 + mt * 16 + fg * 4;
#pragma unroll
        for (int r = 0; r < 4; ++r) {
          a.Wfb[(size_t)(rowb + r) * 512 + col] = f2bf(acc[mt][nt][r]);
        }
      }
    }
    return;
  }
  bx -= 64;
  if (bx < 2048) {
    int row = bx;
    if (row < 1024) {
      ln_body(a.enc + (size_t)row * 512, a.g_ec, a.b_ec,
              a.f_n + (size_t)row * 512, t);
    } else {
      row -= 1024;
      stats_body(a.dec + (size_t)row * 512, a.md, a.q2d,
                 a.dec_b + (size_t)row * 512, t, row);
    }
    return;
  }
  bx -= 2048;
  if (bx < 256) {
    // early casts: 4 jobs x 262144 elems, single shot, 16 elems/thread
    int e = ((bx << 8) | t) << 4;
    int jj = e >> 18;
    int i = e & 262143;
    const CastJob cj = a.cast[jj];
    const float* s = cj.src + i;
    float4 v0 = *(const float4*)s;
    float4 v1 = *(const float4*)(s + 4);
    float4 v2 = *(const float4*)(s + 8);
    float4 v3 = *(const float4*)(s + 12);
    if (cj.cs) {
      int k = i & 511;
      float4 c0 = *(const float4*)(cj.cs + k);
      float4 c1 = *(const float4*)(cj.cs + k + 4);
      float4 c2 = *(const float4*)(cj.cs + k + 8);
      float4 c3 = *(const float4*)(cj.cs + k + 12);
      v0.x *= c0.x; v0.y *= c0.y; v0.z *= c0.z; v0.w *= c0.w;
      v1.x *= c1.x; v1.y *= c1.y; v1.z *= c1.z; v1.w *= c1.w;
      v2.x *= c2.x; v2.y *= c2.y; v2.z *= c2.z; v2.w *= c2.w;
      v3.x *= c3.x; v3.y *= c3.y; v3.z *= c3.z; v3.w *= c3.w;
    }
    u16x8 o0 = {f2bf(v0.x), f2bf(v0.y), f2bf(v0.z), f2bf(v0.w),
                f2bf(v1.x), f2bf(v1.y), f2bf(v1.z), f2bf(v1.w)};
    u16x8 o1 = {f2bf(v2.x), f2bf(v2.y), f2bf(v2.z), f2bf(v2.w),
                f2bf(v3.x), f2bf(v3.y), f2bf(v3.z), f2bf(v3.w)};
    *(u16x8*)(cj.dst + i) = o0;
    *(u16x8*)(cj.dst + i + 8) = o1;
    return;
  }
  bx -= 256;
  if (bx < 128) {
    int n = bx * 4 + (t >> 6);
    int lane = t & 63;
    const float* wk = a.Wk + (size_t)n * 512;
    const float* wv = a.Wv + (size_t)n * 512;
    const float* wo = a.WoA + (size_t)n * 512;
    float uk = 0.f, uv = 0.f, ck = 0.f, cv = 0.f, bfa = 0.f;
#pragma unroll
    for (int k0 = 0; k0 < 512; k0 += 64) {
      int k = k0 + lane;
      float x = wk[k], y = wv[k], gg = a.g_dci[k], bb = a.b_dci[k];
      uk += x * gg; ck += x * bb;
      uv += y * gg; cv += y * bb;
      bfa += wo[k] * a.bv2[k];
    }
    uk = wsum(uk); uv = wsum(uv); ck = wsum(ck); cv = wsum(cv);
    bfa = wsum(bfa);
    if (lane == 0) {
      a.u_k[n] = uk; a.u_v[n] = uv;
      a.c_k[n] = ck + a.bk[n]; a.c_v[n] = cv + a.bv[n];
      a.bf_out[n] = bfa + a.bo2[n];
    }
    return;
  }
  for (int i = t; i < a.zcount; i += 256) a.zbase[i] = 0.f;
}

// ---------------- unified batched bf16 MFMA GEMM ----------------------------
struct GemmJob {
  const unsigned short* X;   // bf16 A (when Xf==null)
  const float* Xf;           // fp32 A with fused LN (overrides X)
  const float* Asum; const float* Asq;  // per-row sum / sum-of-squares
  const float* g; const float* be;      // LN gamma/beta over K (=512)
  const unsigned short* W;
  const float* bias;
  const float* resid;
  float* Y;
  unsigned short* Ybf;
  float* Ssum; float* Ssq;   // epilogue row-stat accumulators (atomics)
  float scale;
  int relu;
};
struct MrJob {
  const unsigned short* A; const unsigned short* B;
  const float* md; const float* q2d;
  const float* ts; const float* tsq;   // raw sums (divide by 512)
  float* mArr; float* rArr;
};
struct PoolJob {
  const float* Ed; const float* Et; const float* pv; const float* dec;
  const unsigned short* tbf; float* dec1; float* d1s; float* d1q;
};
struct GemmBatch {
  GemmJob j[5];
  MrJob mr;
  CastPage cp[25];
  int cast_total;
  PoolJob pl;
};

__device__ inline u16x8 fold_pack(float4 va, float4 vb, const float* gp,
                                  const float* bp, float m, float ri) {
  float4 g0 = *(const float4*)gp;
  float4 g1 = *(const float4*)(gp + 4);
  float4 e0 = *(const float4*)bp;
  float4 e1 = *(const float4*)(bp + 4);
  u16x8 o;
  o[0] = f2bf((va.x - m) * ri * g0.x + e0.x);
  o[1] = f2bf((va.y - m) * ri * g0.y + e0.y);
  o[2] = f2bf((va.z - m) * ri * g0.z + e0.z);
  o[3] = f2bf((va.w - m) * ri * g0.w + e0.w);
  o[4] = f2bf((vb.x - m) * ri * g1.x + e1.x);
  o[5] = f2bf((vb.y - m) * ri * g1.y + e1.y);
  o[6] = f2bf((vb.z - m) * ri * g1.z + e1.z);
  o[7] = f2bf((vb.w - m) * ri * g1.w + e1.w);
  return o;
}

// Pool body: one block per (i,b); 256 threads.
__device__ void pool_body(const PoolJob& p, int i, int b) {
  __shared__ float esh[64], wsh[64], pps[8];
  const int t = threadIdx.x;
  int wave = t >> 6, lane = t & 63;
  float edv[8], pvv[8];
  const float* ed = p.Ed + (size_t)(i * 16 + b) * 512;
#pragma unroll
  for (int c = 0; c < 8; ++c) {
    edv[c] = ed[c * 64 + lane];
    pvv[c] = p.pv[c * 64 + lane];
  }
#pragma unroll 1
  for (int jl = 0; jl < 16; ++jl) {
    int j = wave * 16 + jl;
    const float* et = p.Et + (size_t)(j * 16 + b) * 512;
    float s = 0.f;
#pragma unroll
    for (int c = 0; c < 8; ++c) {
      float x = edv[c] + et[c * 64 + lane];
      float e2 = __expf(2.f * x);
      float th = 1.f - 2.f * __builtin_amdgcn_rcpf(e2 + 1.f);  // tanh
      s += th * pvv[c];
    }
    s = wsum(s);
    if (lane == 0) esh[j] = s;
  }
  __syncthreads();
  if (t < 64) {
    float e = esh[t];
    float mx = wmax(e);
    float ex = __expf(e - mx);
    float se = wsum(ex);
    wsh[t] = ex / se;
  }
  __syncthreads();
  size_t rowib = (size_t)(i * 16 + b) * 512;
  int d2 = t * 2;
  float2 dv = *(const float2*)(p.dec + rowib + d2);
  float acc0 = dv.x, acc1 = dv.y;
#pragma unroll 8
  for (int j2 = 0; j2 < 64; ++j2) {
    const unsigned short* tp = p.tbf + (size_t)(j2 * 16 + b) * 512 + d2;
    float w = wsh[j2];
    acc0 += w * bf2f(tp[0]);
    acc1 += w * bf2f(tp[1]);
  }
  float2 ov = {acc0, acc1};
  *(float2*)(p.dec1 + rowib + d2) = ov;
  float s1 = acc0 + acc1;
  float s2v = acc0 * acc0 + acc1 * acc1;
  s1 = wsum(s1);
  s2v = wsum(s2v);
  if (lane == 0) { pps[wave] = s1; pps[4 + wave] = s2v; }
  __syncthreads();
  if (t == 0) {
    p.d1s[i * 16 + b] = pps[0] + pps[1] + pps[2] + pps[3];
    p.d1q[i * 16 + b] = pps[4] + pps[5] + pps[6] + pps[7];
  }
}

// EXTRA: 0=none, 1=cast pages at z>=xz, 2=mr slice at z==xz, 3=pool at z>=xz
// NW: waves per block. BMT: A-tile rows (64 or 128; 128 requires NW=8).
//  NW4/BMT64 : wave-tile 32x32 (MT=2)   NW8/BMT64 : wave-tile 16x32 (MT=1)
//  NW8/BMT128: wave-tile 32x32 (MT=2), 64 MFMA/block/K-step
template <int EXTRA, bool FOLD, bool STATS, int NW, int BMT>
__global__ __launch_bounds__(NW * 64) void gemm_bf16(GemmBatch gb, int M,
                                                     int N, int K, int xz) {
  const int t = threadIdx.x;
  constexpr int NT = NW * 64;
  if constexpr (EXTRA == 1) {
    if ((int)blockIdx.z >= xz) {
      const int nbz = (int)(gridDim.x * gridDim.y);
      const int bid = ((int)blockIdx.z - xz) * nbz +
                      (int)blockIdx.y * (int)gridDim.x + (int)blockIdx.x;
      const int nthr = ((int)gridDim.z - xz) * nbz * NT;
      for (int base = (bid * NT + t) * 16; base < gb.cast_total;
           base += nthr * 16) {
        int page = base >> 18;
        int off = base & 262143;
        const float* s = gb.cp[page].src + off;
        unsigned short* d = gb.cp[page].dst + off;
        float4 v0 = *(const float4*)s;
        float4 v1 = *(const float4*)(s + 4);
        float4 v2 = *(const float4*)(s + 8);
        float4 v3 = *(const float4*)(s + 12);
        u16x8 o0 = {f2bf(v0.x), f2bf(v0.y), f2bf(v0.z), f2bf(v0.w),
                    f2bf(v1.x), f2bf(v1.y), f2bf(v1.z), f2bf(v1.w)};
        u16x8 o1 = {f2bf(v2.x), f2bf(v2.y), f2bf(v2.z), f2bf(v2.w),
                    f2bf(v3.x), f2bf(v3.y), f2bf(v3.z), f2bf(v3.w)};
        *(u16x8*)d = o0;
        *(u16x8*)(d + 8) = o1;
      }
      return;
    }
  }
  if constexpr (EXTRA == 3) {
    if ((int)blockIdx.z >= xz) {
      int pb = ((int)blockIdx.z - xz) * (int)(gridDim.x * gridDim.y) +
               (int)blockIdx.y * (int)gridDim.x + (int)blockIdx.x;
      pool_body(gb.pl, pb & 63, pb >> 6);
      return;
    }
  }
  __shared__ unsigned short As[BMT][72];  // 144B stride = 9x16B aligned
  __shared__ unsigned short Bs[64][72];
  const int lane = t & 63;
  const int wave = t >> 6;
  const int wr = wave >> 1;  // NW4: 0..1; NW8: 0..3
  const int wc = wave & 1;
  const int fr = lane & 15;
  const int fg = lane >> 4;
  constexpr int MT = (NW == 4 || BMT == 128) ? 2 : 1;
  constexpr int RB = MT * 16;  // wave row-band size
  const int r0 = t >> 3, o0 = (t & 7) * 8;
  const int r1 = ((t + 256) >> 3) & 63, o1 = ((t + 256) & 7) * 8;

  if constexpr (EXTRA == 2) {
    if ((int)blockIdx.z == xz) {
      // per-(j,i,b) LN stats via MFMA: S[i][j] = dec_b[i,b,:]·tb_b[j,b,:]
      const int bb = blockIdx.y * gridDim.x + blockIdx.x;
      if (bb >= 16) return;
      const unsigned short* Ap = gb.mr.A + (size_t)bb * 512;
      const unsigned short* Bp = gb.mr.B + (size_t)bb * 512;
      f32x4 acc[2][2] = {};
      for (int k0 = 0; k0 < 512; k0 += 64) {
        *(u16x8*)&As[r0][o0] = *(const u16x8*)&Ap[(size_t)r0 * 8192 + k0 + o0];
        *(u16x8*)&As[r1][o1] = *(const u16x8*)&Ap[(size_t)r1 * 8192 + k0 + o1];
        *(u16x8*)&Bs[r0][o0] = *(const u16x8*)&Bp[(size_t)r0 * 8192 + k0 + o0];
        *(u16x8*)&Bs[r1][o1] = *(const u16x8*)&Bp[(size_t)r1 * 8192 + k0 + o1];
        __syncthreads();
#pragma unroll
        for (int ks = 0; ks < 2; ++ks) {
          int kk = ks * 32 + fg * 8;
          bf16x8 a0 = *(const bf16x8*)&As[wr * 32 + fr][kk];
          bf16x8 a1 = *(const bf16x8*)&As[wr * 32 + 16 + fr][kk];
          bf16x8 b0 = *(const bf16x8*)&Bs[wc * 32 + fr][kk];
          bf16x8 b1 = *(const bf16x8*)&Bs[wc * 32 + 16 + fr][kk];
          acc[0][0] = __builtin_amdgcn_mfma_f32_16x16x32_bf16(a0, b0, acc[0][0], 0, 0, 0);
          acc[0][1] = __builtin_amdgcn_mfma_f32_16x16x32_bf16(a0, b1, acc[0][1], 0, 0, 0);
          acc[1][0] = __builtin_amdgcn_mfma_f32_16x16x32_bf16(a1, b0, acc[1][0], 0, 0, 0);
          acc[1][1] = __builtin_amdgcn_mfma_f32_16x16x32_bf16(a1, b1, acc[1][1], 0, 0, 0);
        }
        __syncthreads();
      }
#pragma unroll
      for (int nt = 0; nt < 2; ++nt) {
        int j = wc * 32 + nt * 16 + fr;
        float mtv = gb.mr.ts[j * 16 + bb] * (1.f / 512.f);
        float qtv = gb.mr.tsq[j * 16 + bb] * (1.f / 512.f);
#pragma unroll
        for (int mt = 0; mt < 2; ++mt) {
          int ibase = wr * 32 + mt * 16 + fg * 4;
#pragma unroll
          for (int r = 0; r < 4; ++r) {
            int i = ibase + r;
            float s = acc[mt][nt][r];
            float mean = gb.mr.md[i * 16 + bb] + mtv;
            float msq = gb.mr.q2d[i * 16 + bb] + qtv + s * (2.f / 512.f);
            int idx = bb * 4096 + j * 64 + i;
            gb.mr.mArr[idx] = mean;
            gb.mr.rArr[idx] = rsqrtf(msq - mean * mean + 1e-5f);
          }
        }
      }
      return;
    }
  }

  const GemmJob jb = gb.j[blockIdx.z];
  const int bm = blockIdx.y * BMT;
  const int bn = blockIdx.x * 64;
  f32x4 acc[MT][2] = {};
  const unsigned short* Wp = jb.W + (size_t)bn * K;
  // second A-row for each staging scheme
  const int ra = (NW == 4) ? r1 : r0 + 64;   // (BMT==128 uses r0+64)
  const int oa = (NW == 4) ? o1 : o0;

  u16x8 xa0, xa1;
  float4 fa0a, fa0b, fa1a, fa1b;
  float lm0 = 0.f, lr0i = 0.f, lm1 = 0.f, lr1i = 0.f;
  const unsigned short* Xp = nullptr;
  constexpr bool A2 = (NW == 4) || (BMT == 128);  // two A loads per thread
  if constexpr (FOLD) {
    float s = jb.Asum[bm + r0], q = jb.Asq[bm + r0];
    lm0 = s * (1.f / 512.f);
    lr0i = rsqrtf(q * (1.f / 512.f) - lm0 * lm0 + 1e-5f);
    if constexpr (A2) {
      s = jb.Asum[bm + ra]; q = jb.Asq[bm + ra];
      lm1 = s * (1.f / 512.f);
      lr1i = rsqrtf(q * (1.f / 512.f) - lm1 * lm1 + 1e-5f);
    }
    const float* p0 = jb.Xf + (size_t)(bm + r0) * K + o0;
    fa0a = *(const float4*)p0; fa0b = *(const float4*)(p0 + 4);
    if constexpr (A2) {
      const float* p1 = jb.Xf + (size_t)(bm + ra) * K + oa;
      fa1a = *(const float4*)p1; fa1b = *(const float4*)(p1 + 4);
    }
  } else {
    Xp = jb.X + (size_t)bm * K;
    xa0 = *(const u16x8*)&Xp[(size_t)r0 * K + o0];
    if constexpr (A2) xa1 = *(const u16x8*)&Xp[(size_t)ra * K + oa];
  }
  u16x8 wa0 = *(const u16x8*)&Wp[(size_t)r0 * K + o0];
  u16x8 wa1;
  if constexpr (NW == 4) wa1 = *(const u16x8*)&Wp[(size_t)r1 * K + o1];

  for (int k0 = 0; k0 < K; k0 += 64) {
    if constexpr (FOLD) {
      *(u16x8*)&As[r0][o0] = fold_pack(fa0a, fa0b, jb.g + k0 + o0, jb.be + k0 + o0, lm0, lr0i);
      if constexpr (A2)
        *(u16x8*)&As[ra][oa] = fold_pack(fa1a, fa1b, jb.g + k0 + oa, jb.be + k0 + oa, lm1, lr1i);
    } else {
      *(u16x8*)&As[r0][o0] = xa0;
      if constexpr (A2) *(u16x8*)&As[ra][oa] = xa1;
    }
    *(u16x8*)&Bs[r0][o0] = wa0;
    if constexpr (NW == 4) *(u16x8*)&Bs[r1][o1] = wa1;
    __syncthreads();
    if (k0 + 64 < K) {
      const int kn = k0 + 64;
      if constexpr (FOLD) {
        const float* p0 = jb.Xf + (size_t)(bm + r0) * K + kn + o0;
        fa0a = *(const float4*)p0; fa0b = *(const float4*)(p0 + 4);
        if constexpr (A2) {
          const float* p1 = jb.Xf + (size_t)(bm + ra) * K + kn + oa;
          fa1a = *(const float4*)p1; fa1b = *(const float4*)(p1 + 4);
        }
      } else {
        xa0 = *(const u16x8*)&Xp[(size_t)r0 * K + kn + o0];
        if constexpr (A2) xa1 = *(const u16x8*)&Xp[(size_t)ra * K + kn + oa];
      }
      wa0 = *(const u16x8*)&Wp[(size_t)r0 * K + kn + o0];
      if constexpr (NW == 4) wa1 = *(const u16x8*)&Wp[(size_t)r1 * K + kn + o1];
    }
#pragma unroll
    for (int ks = 0; ks < 2; ++ks) {
      int kk = ks * 32 + fg * 8;
      bf16x8 b0 = *(const bf16x8*)&Bs[wc * 32 + fr][kk];
      bf16x8 b1 = *(const bf16x8*)&Bs[wc * 32 + 16 + fr][kk];
      if constexpr (MT == 2) {
        bf16x8 a0 = *(const bf16x8*)&As[wr * 32 + fr][kk];
        bf16x8 a1 = *(const bf16x8*)&As[wr * 32 + 16 + fr][kk];
        acc[0][0] = __builtin_amdgcn_mfma_f32_16x16x32_bf16(a0, b0, acc[0][0], 0, 0, 0);
        acc[0][1] = __builtin_amdgcn_mfma_f32_16x16x32_bf16(a0, b1, acc[0][1], 0, 0, 0);
        acc[1][0] = __builtin_amdgcn_mfma_f32_16x16x32_bf16(a1, b0, acc[1][0], 0, 0, 0);
        acc[1][1] = __builtin_amdgcn_mfma_f32_16x16x32_bf16(a1, b1, acc[1][1], 0, 0, 0);
      } else {
        bf16x8 a0 = *(const bf16x8*)&As[wr * 16 + fr][kk];
        acc[0][0] = __builtin_amdgcn_mfma_f32_16x16x32_bf16(a0, b0, acc[0][0], 0, 0, 0);
        acc[0][1] = __builtin_amdgcn_mfma_f32_16x16x32_bf16(a0, b1, acc[0][1], 0, 0, 0);
      }
    }
    __syncthreads();
  }
  float rsum[MT][4], rsq[MT][4];
  if constexpr (STATS) {
#pragma unroll
    for (int mt = 0; mt < MT; ++mt)
#pragma unroll
      for (int r = 0; r < 4; ++r) { rsum[mt][r] = 0.f; rsq[mt][r] = 0.f; }
  }
#pragma unroll
  for (int mt = 0; mt < MT; ++mt) {
#pragma unroll
    for (int nt = 0; nt < 2; ++nt) {
      int col = bn + wc * 32 + nt * 16 + fr;
      int rowb = bm + wr * RB + mt * 16 + fg * 4;
      float bia = jb.bias ? jb.bias[col] : 0.f;
#pragma unroll
      for (int r = 0; r < 4; ++r) {
        float v = (acc[mt][nt][r] + bia) * jb.scale;
        if (jb.relu) v = fmaxf(v, 0.f);
        if (jb.resid) v += jb.resid[(size_t)(rowb + r) * N + col];
        size_t idx = (size_t)(rowb + r) * N + col;
        if (jb.Y) jb.Y[idx] = v;
        if (jb.Ybf) jb.Ybf[idx] = f2bf(v);
        if constexpr (STATS) { rsum[mt][r] += v; rsq[mt][r] += v * v; }
      }
    }
  }
  if constexpr (STATS) {
    if (jb.Ssum) {
#pragma unroll
      for (int mt = 0; mt < MT; ++mt)
#pragma unroll
        for (int r = 0; r < 4; ++r) {
          float s = rsum[mt][r], q = rsq[mt][r];
#pragma unroll
          for (int o = 1; o < 16; o <<= 1) {
            s += __shfl_xor(s, o);
            q += __shfl_xor(q, o);
          }
          if (fr == 0) {
            int row = bm + wr * RB + mt * 16 + fg * 4 + r;
            atomicAdd(&jb.Ssum[row], s);
            atomicAdd(&jb.Ssq[row], q);
          }
        }
    }
  }
}

// ------- ec cross-attention: 256 blocks x 128 thr, j-split, global ms/rs ----
__global__ __launch_bounds__(128) void ec_attn(
    const unsigned short* __restrict__ Qe, const unsigned short* __restrict__ Kd,
    const unsigned short* __restrict__ Kt, const unsigned short* __restrict__ Vd,
    const unsigned short* __restrict__ Vt, const float* __restrict__ u_k,
    const float* __restrict__ u_v, const float* __restrict__ c_k,
    const float* __restrict__ c_v, const float* __restrict__ mArr,
    const float* __restrict__ rArr, unsigned short* __restrict__ O) {
  int bx = blockIdx.x;
  int h = bx & 7;
  int b = (bx >> 3) & 15;
  int jlo = (bx >> 7) * 32;
  __shared__ unsigned short Qs[32][72];
  __shared__ unsigned short Ks[64][72];
  __shared__ unsigned short VdT[64][72];
  __shared__ unsigned short Ps[32][72];
  __shared__ float stp[32][4], sup[32][4], scp[32][4];
  __shared__ float stv[32], suv[32], scv[32], swv[32], swmv[32];
  int t = threadIdx.x;
  {
    int row = t >> 2;         // 0..31
    int qt = t & 3;
    int cb = qt * 16;
    size_t base = (size_t)((jlo + row) * 16 + b) * 512 + h * 64 + cb;
    u16x8 q0 = *(const u16x8*)(Qe + base);
    u16x8 q1 = *(const u16x8*)(Qe + base + 8);
    u16x8 kt0 = *(const u16x8*)(Kt + base);
    u16x8 kt1 = *(const u16x8*)(Kt + base + 8);
    *(u16x8*)&Qs[row][cb] = q0;
    *(u16x8*)&Qs[row][cb + 8] = q1;
    float st_ = 0.f, su_ = 0.f, sc_ = 0.f;
#pragma unroll
    for (int jj = 0; jj < 8; ++jj) {
      float qa = bf2f(q0[jj]), qb = bf2f(q1[jj]);
      st_ += qa * bf2f(kt0[jj]) + qb * bf2f(kt1[jj]);
      su_ += qa * u_k[h * 64 + cb + jj] + qb * u_k[h * 64 + cb + 8 + jj];
      sc_ += qa * c_k[h * 64 + cb + jj] + qb * c_k[h * 64 + cb + 8 + jj];
    }
    stp[row][qt] = st_;
    sup[row][qt] = su_;
    scp[row][qt] = sc_;
    int row2 = t >> 1;        // 0..63
    int c0 = (t & 1) * 32;
    size_t base2 = (size_t)(row2 * 16 + b) * 512 + h * 64 + c0;
    u16x8 k0 = *(const u16x8*)(Kd + base2);
    u16x8 k1 = *(const u16x8*)(Kd + base2 + 8);
    u16x8 k2 = *(const u16x8*)(Kd + base2 + 16);
    u16x8 k3 = *(const u16x8*)(Kd + base2 + 24);
    u16x8 v0 = *(const u16x8*)(Vd + base2);
    u16x8 v1 = *(const u16x8*)(Vd + base2 + 8);
    u16x8 v2 = *(const u16x8*)(Vd + base2 + 16);
    u16x8 v3 = *(const u16x8*)(Vd + base2 + 24);
    *(u16x8*)&Ks[row2][c0] = k0;
    *(u16x8*)&Ks[row2][c0 + 8] = k1;
    *(u16x8*)&Ks[row2][c0 + 16] = k2;
    *(u16x8*)&Ks[row2][c0 + 24] = k3;
#pragma unroll
    for (int jj = 0; jj < 8; ++jj) VdT[c0 + jj][row2] = v0[jj];
#pragma unroll
    for (int jj = 0; jj < 8; ++jj) VdT[c0 + 8 + jj][row2] = v1[jj];
#pragma unroll
    for (int jj = 0; jj < 8; ++jj) VdT[c0 + 16 + jj][row2] = v2[jj];
#pragma unroll
    for (int jj = 0; jj < 8; ++jj) VdT[c0 + 24 + jj][row2] = v3[jj];
  }
  __syncthreads();
  if (t < 32) {
    stv[t] = stp[t][0] + stp[t][1] + stp[t][2] + stp[t][3];
    suv[t] = sup[t][0] + sup[t][1] + sup[t][2] + sup[t][3];
    scv[t] = scp[t][0] + scp[t][1] + scp[t][2] + scp[t][3];
  }
  __syncthreads();
  int wave = t >> 6, lane = t & 63;
  int fr = lane & 15, fg = lane >> 4;
  f32x4 sacc[4] = {};
  bf16x8 aq0 = *(const bf16x8*)&Qs[wave * 16 + fr][fg * 8];
  bf16x8 aq1 = *(const bf16x8*)&Qs[wave * 16 + fr][32 + fg * 8];
#pragma unroll
  for (int nt = 0; nt < 4; ++nt) {
    bf16x8 b0 = *(const bf16x8*)&Ks[nt * 16 + fr][fg * 8];
    bf16x8 b1 = *(const bf16x8*)&Ks[nt * 16 + fr][32 + fg * 8];
    sacc[nt] = __builtin_amdgcn_mfma_f32_16x16x32_bf16(aq0, b0, sacc[nt], 0, 0, 0);
    sacc[nt] = __builtin_amdgcn_mfma_f32_16x16x32_bf16(aq1, b1, sacc[nt], 0, 0, 0);
  }
#pragma unroll
  for (int r = 0; r < 4; ++r) {
    int lj = wave * 16 + fg * 4 + r;
    int gj = jlo + lj;
    const float* mrow = mArr + (size_t)b * 4096 + gj * 64;
    const float* rrow = rArr + (size_t)b * 4096 + gj * 64;
    float m0 = mrow[fr], m1 = mrow[16 + fr], m2 = mrow[32 + fr], m3 = mrow[48 + fr];
    float r0v = rrow[fr], r1v = rrow[16 + fr], r2v = rrow[32 + fr], r3v = rrow[48 + fr];
    float stj = stv[lj], suj = suv[lj], scj = scv[lj];
    float a0 = r0v * (sacc[0][r] + stj - m0 * suj) + scj;
    float a1 = r1v * (sacc[1][r] + stj - m1 * suj) + scj;
    float a2 = r2v * (sacc[2][r] + stj - m2 * suj) + scj;
    float a3 = r3v * (sacc[3][r] + stj - m3 * suj) + scj;
    float mx = fmaxf(fmaxf(a0, a1), fmaxf(a2, a3));
#pragma unroll
    for (int o = 1; o < 16; o <<= 1) mx = fmaxf(mx, __shfl_xor(mx, o));
    a0 = __expf(a0 - mx);
    a1 = __expf(a1 - mx);
    a2 = __expf(a2 - mx);
    a3 = __expf(a3 - mx);
    float se = a0 + a1 + a2 + a3;
#pragma unroll
    for (int o = 1; o < 16; o <<= 1) se += __shfl_xor(se, o);
    float inv = 1.f / se;
    float w0 = a0 * inv * r0v;
    float w1 = a1 * inv * r1v;
    float w2 = a2 * inv * r2v;
    float w3 = a3 * inv * r3v;
    float sw = w0 + w1 + w2 + w3;
    float swm = w0 * m0 + w1 * m1 + w2 * m2 + w3 * m3;
#pragma unroll
    for (int o = 1; o < 16; o <<= 1) {
      sw += __shfl_xor(sw, o);
      swm += __shfl_xor(swm, o);
    }
    Ps[lj][fr] = f2bf(w0);
    Ps[lj][16 + fr] = f2bf(w1);
    Ps[lj][32 + fr] = f2bf(w2);
    Ps[lj][48 + fr] = f2bf(w3);
    if (fr == 0) {
      swv[lj] = sw;
      swmv[lj] = swm;
    }
  }
  f32x4 oc[4] = {};
  bf16x8 ap0 = *(const bf16x8*)&Ps[wave * 16 + fr][fg * 8];
  bf16x8 ap1 = *(const bf16x8*)&Ps[wave * 16 + fr][32 + fg * 8];
#pragma unroll
  for (int nt = 0; nt < 4; ++nt) {
    bf16x8 b0 = *(const bf16x8*)&VdT[nt * 16 + fr][fg * 8];
    bf16x8 b1 = *(const bf16x8*)&VdT[nt * 16 + fr][32 + fg * 8];
    oc[nt] = __builtin_amdgcn_mfma_f32_16x16x32_bf16(ap0, b0, oc[nt], 0, 0, 0);
    oc[nt] = __builtin_amdgcn_mfma_f32_16x16x32_bf16(ap1, b1, oc[nt], 0, 0, 0);
  }
#pragma unroll
  for (int nt = 0; nt < 4; ++nt) {
    int d = nt * 16 + fr;
    float uvd = u_v[h * 64 + d];
    float cvd = c_v[h * 64 + d];
#pragma unroll
    for (int r = 0; r < 4; ++r) {
      int lj = wave * 16 + fg * 4 + r;
      int gj = jlo + lj;
      size_t gidx = (size_t)(gj * 16 + b) * 512 + h * 64 + d;
      float o = oc[nt][r] + swv[lj] * bf2f(Vt[gidx]) - swmv[lj] * uvd + cvd;
      O[gidx] = f2bf(o);
    }
  }
}

// ------- MFMA self-attention: 512 blocks x 128 thr (q-split) ----------------
__global__ __launch_bounds__(128) void self_attn(
    const unsigned short* __restrict__ QKVe, unsigned short* __restrict__ Oe,
    const unsigned short* __restrict__ QKVd, unsigned short* __restrict__ Od) {
  const unsigned short* QKV = blockIdx.z ? QKVd : QKVe;
  unsigned short* O = blockIdx.z ? Od : Oe;
  int h = blockIdx.x & 7;
  int b = blockIdx.x >> 3;
  int qlo = blockIdx.y * 32;
  __shared__ unsigned short Qs[32][72];
  __shared__ unsigned short Ksh[64][72];
  __shared__ unsigned short VT[64][72];
  __shared__ unsigned short Ps[32][72];
  int t = threadIdx.x;
  {
    int row = t >> 2;        // 0..31 (our q rows)
    int cb = (t & 3) * 16;
    const unsigned short* src =
        QKV + (size_t)((qlo + row) * 16 + b) * 1536 + h * 64 + cb;
    u16x8 q0 = *(const u16x8*)(src);
    u16x8 q1 = *(const u16x8*)(src + 8);
    *(u16x8*)&Qs[row][cb] = q0;
    *(u16x8*)&Qs[row][cb + 8] = q1;
    int row2 = t >> 1;       // 0..63 (all kv rows)
    int c0 = (t & 1) * 32;
    const unsigned short* src2 =
        QKV + (size_t)(row2 * 16 + b) * 1536 + h * 64 + c0;
    u16x8 k0 = *(const u16x8*)(src2 + 512);
    u16x8 k1 = *(const u16x8*)(src2 + 520);
    u16x8 k2 = *(const u16x8*)(src2 + 528);
    u16x8 k3 = *(const u16x8*)(src2 + 536);
    u16x8 v0 = *(const u16x8*)(src2 + 1024);
    u16x8 v1 = *(const u16x8*)(src2 + 1032);
    u16x8 v2 = *(const u16x8*)(src2 + 1040);
    u16x8 v3 = *(const u16x8*)(src2 + 1048);
    *(u16x8*)&Ksh[row2][c0] = k0;
    *(u16x8*)&Ksh[row2][c0 + 8] = k1;
    *(u16x8*)&Ksh[row2][c0 + 16] = k2;
    *(u16x8*)&Ksh[row2][c0 + 24] = k3;
#pragma unroll
    for (int jj = 0; jj < 8; ++jj) VT[c0 + jj][row2] = v0[jj];
#pragma unroll
    for (int jj = 0; jj < 8; ++jj) VT[c0 + 8 + jj][row2] = v1[jj];
#pragma unroll
    for (int jj = 0; jj < 8; ++jj) VT[c0 + 16 + jj][row2] = v2[jj];
#pragma unroll
    for (int jj = 0; jj < 8; ++jj) VT[c0 + 24 + jj][row2] = v3[jj];
  }
  __syncthreads();
  int wave = t >> 6, lane = t & 63;
  int fr = lane & 15, fg = lane >> 4;
  f32x4 sc[4] = {};
  bf16x8 aq0 = *(const bf16x8*)&Qs[wave * 16 + fr][fg * 8];
  bf16x8 aq1 = *(const bf16x8*)&Qs[wave * 16 + fr][32 + fg * 8];
#pragma unroll
  for (int nt = 0; nt < 4; ++nt) {
    bf16x8 b0 = *(const bf16x8*)&Ksh[nt * 16 + fr][fg * 8];
    bf16x8 b1 = *(const bf16x8*)&Ksh[nt * 16 + fr][32 + fg * 8];
    sc[nt] = __builtin_amdgcn_mfma_f32_16x16x32_bf16(aq0, b0, sc[nt], 0, 0, 0);
    sc[nt] = __builtin_amdgcn_mfma_f32_16x16x32_bf16(aq1, b1, sc[nt], 0, 0, 0);
  }
#pragma unroll
  for (int r = 0; r < 4; ++r) {
    float a0 = sc[0][r] * 0.125f, a1 = sc[1][r] * 0.125f;
    float a2 = sc[2][r] * 0.125f, a3 = sc[3][r] * 0.125f;
    float mx = fmaxf(fmaxf(a0, a1), fmaxf(a2, a3));
#pragma unroll
    for (int o = 1; o < 16; o <<= 1) mx = fmaxf(mx, __shfl_xor(mx, o));
    a0 = __expf(a0 - mx);
    a1 = __expf(a1 - mx);
    a2 = __expf(a2 - mx);
    a3 = __expf(a3 - mx);
    float se = a0 + a1 + a2 + a3;
#pragma unroll
    for (int o = 1; o < 16; o <<= 1) se += __shfl_xor(se, o);
    float inv = 1.f / se;
    int prow = wave * 16 + fg * 4 + r;
    Ps[prow][0 + fr] = f2bf(a0 * inv);
    Ps[prow][16 + fr] = f2bf(a1 * inv);
    Ps[prow][32 + fr] = f2bf(a2 * inv);
    Ps[prow][48 + fr] = f2bf(a3 * inv);
  }
  f32x4 oc[4] = {};
  bf16x8 ap0 = *(const bf16x8*)&Ps[wave * 16 + fr][fg * 8];
  bf16x8 ap1 = *(const bf16x8*)&Ps[wave * 16 + fr][32 + fg * 8];
#pragma unroll
  for (int nt = 0; nt < 4; ++nt) {
    bf16x8 b0 = *(const bf16x8*)&VT[nt * 16 + fr][fg * 8];
    bf16x8 b1 = *(const bf16x8*)&VT[nt * 16 + fr][32 + fg * 8];
    oc[nt] = __builtin_amdgcn_mfma_f32_16x16x32_bf16(ap0, b0, oc[nt], 0, 0, 0);
    oc[nt] = __builtin_amdgcn_mfma_f32_16x16x32_bf16(ap1, b1, oc[nt], 0, 0, 0);
  }
#pragma unroll
  for (int nt = 0; nt < 4; ++nt) {
#pragma unroll
    for (int r = 0; r < 4; ++r) {
      int q = qlo + wave * 16 + fg * 4 + r;
      int d = nt * 16 + fr;
      O[(size_t)(q * 16 + b) * 512 + h * 64 + d] = f2bf(oc[nt][r]);
    }
  }
}

extern "C" void kernel_launch(void* const* d_in, const int* in_sizes, int n_in,
                              void* d_out, int out_size, void* d_ws,
                              size_t ws_size, hipStream_t stream) {
  const float* enc = (const float*)d_in[0];
  const float* dec = (const float*)d_in[1];
  const float* ec_Wi = (const float*)d_in[2];
  const float* ec_bi = (const float*)d_in[3];
  const float* ec_Wo = (const float*)d_in[4];
  const float* ec_bo = (const float*)d_in[5];
  const float* dc_Wi = (const float*)d_in[6];
  const float* dc_bi = (const float*)d_in[7];
  const float* dc_Wo = (const float*)d_in[8];
  const float* dc_bo = (const float*)d_in[9];
  const float* es_Wi = (const float*)d_in[10];
  const float* es_bi = (const float*)d_in[11];
  const float* es_Wo = (const float*)d_in[12];
  const float* es_bo = (const float*)d_in[13];
  const float* ds_Wi = (const float*)d_in[14];
  const float* ds_bi = (const float*)d_in[15];
  const float* ds_Wo = (const float*)d_in[16];
  const float* ds_bo = (const float*)d_in[17];
  const float* eff_W1 = (const float*)d_in[18];
  const float* eff_b1 = (const float*)d_in[19];
  const float* eff_W2 = (const float*)d_in[20];
  const float* eff_b2 = (const float*)d_in[21];
  const float* dff_W1 = (const float*)d_in[22];
  const float* dff_b1 = (const float*)d_in[23];
  const float* dff_W2 = (const float*)d_in[24];
  const float* dff_b2 = (const float*)d_in[25];
  const float* n_ec_g = (const float*)d_in[26];
  const float* n_ec_b = (const float*)d_in[27];
  const float* n_es_g = (const float*)d_in[28];
  const float* n_es_b = (const float*)d_in[29];
  const float* n_ef_g = (const float*)d_in[30];
  const float* n_ef_b = (const float*)d_in[31];
  const float* n_dci_g = (const float*)d_in[34];
  const float* n_dci_b = (const float*)d_in[35];
  const float* n_ds_g = (const float*)d_in[36];
  const float* n_ds_b = (const float*)d_in[37];
  const float* n_df_g = (const float*)d_in[38];
  const float* n_df_b = (const float*)d_in[39];
  const float* pW = (const float*)d_in[40];
  const float* pWb = (const float*)d_in[41];
  const float* pv = (const float*)d_in[42];
  const float* pb = (const float*)d_in[43];

  float* ws = (float*)d_ws;
  const size_t U = 524288;  // 1024*512 elements
  float* Ed = ws + 3 * U;
  float* Et = ws + 7 * U;
  float* enc1 = ws + 8 * U;
  float* dec1 = ws + 9 * U;
  float* enc2 = ws + 10 * U;
  float* dec2 = ws + 11 * U;
  float* sm = ws + 12 * U;
  float* md = sm;
  float* q2d = sm + 1024;
  float* bf = sm + 2048;       // t bias = dc_Wo@dc_bv + dc_bo (512)
  float* u_k = sm + 4096;
  float* u_v = sm + 4608;
  float* c_k = sm + 5120;
  float* c_v = sm + 5632;
  float* mArr = sm + 6144;  // b-major [b][j][i], 65536
  float* rArr = sm + 6144 + 65536;
  // atomic / plain row-stat accumulators (fresh region, zeroed in phase0)
  float* stx = ws + 24 * U;
  float* t_s = stx;            // t row sums
  float* t_sq = stx + 1024;
  float* e1s = stx + 2048;     // enc1
  float* e1q = stx + 3072;
  float* d1s = stx + 4096;     // dec1 (plain store from pool)
  float* d1q = stx + 5120;
  float* e2s = stx + 6144;     // enc2
  float* e2q = stx + 7168;
  float* d2s = stx + 8192;     // dec2
  float* d2q = stx + 9216;
  unsigned short* ub0 = (unsigned short*)ws;
  unsigned short* Qe_b = ub0 + 0 * U;
  unsigned short* Kd_b = ub0 + 1 * U;
  unsigned short* Vd_b = ub0 + 2 * U;
  unsigned short* Kt_b = ub0 + 3 * U;
  unsigned short* Vt_b = ub0 + 4 * U;
  unsigned short* ub = (unsigned short*)(ws + 12 * U + 137216);
  const int W262 = 262144, W786 = 786432, W1M = 1048576;
  unsigned short* w_Wf = ub;            // composite dc_Wo @ dc_Wv (bf16)
  unsigned short* w_ecWq = w_Wf + W262;
  unsigned short* w_ecWkg = w_ecWq + W262;
  unsigned short* w_ecWvg = w_ecWkg + W262;
  unsigned short* w_pW = w_ecWvg + W262;
  unsigned short* w_unused = w_pW + W262;
  unsigned short* w_ecWo = w_unused + W262;
  unsigned short* w_esWi = w_ecWo + W262;
  unsigned short* w_dsWi = w_esWi + W786;
  unsigned short* w_esWo = w_dsWi + W786;
  unsigned short* w_dsWo = w_esWo + W262;
  unsigned short* w_effW1 = w_dsWo + W262;
  unsigned short* w_dffW1 = w_effW1 + W1M;
  unsigned short* w_effW2 = w_dffW1 + W1M;
  unsigned short* w_dffW2 = w_effW2 + W1M;
  unsigned short* actb = w_dffW2 + W1M;
  unsigned short* f_n_b = actb;
  unsigned short* dec_b = actb + 2 * U;
  unsigned short* tb_b = actb + 3 * U;
  unsigned short* Oec_b = actb + 4 * U;
  unsigned short* OaE = dec_b;  // reuse: dec_b dead after L3, tb_b after L5
  unsigned short* OaD = tb_b;
  unsigned short* QKVe_b = (unsigned short*)(ws + 0 * U);
  unsigned short* QKVd_b = (unsigned short*)(ws + 2 * U);
  unsigned short* He_b = (unsigned short*)(ws + 0 * U);
  unsigned short* Hd_b = (unsigned short*)(ws + 2 * U);

  const float* dc_Wv = dc_Wi + 1024 * 512;
  const float* dc_bv = dc_bi + 1024;
  const float* ec_Wq = ec_Wi;
  const float* ec_bq = ec_bi;
  const float* ec_Wk = ec_Wi + 512 * 512;
  const float* ec_bk = ec_bi + 512;
  const float* ec_Wv = ec_Wi + 1024 * 512;
  const float* ec_bv = ec_bi + 1024;

  auto J = [](const unsigned short* X, const unsigned short* W,
              const float* bias, const float* resid, float* Y,
              unsigned short* Ybf, float scale, int relu) {
    GemmJob j{};
    j.X = X; j.W = W; j.bias = bias; j.resid = resid;
    j.Y = Y; j.Ybf = Ybf; j.scale = scale; j.relu = relu;
    return j;
  };
  auto JF = [](const float* Xf, const float* As, const float* Aq,
               const float* g, const float* be, const unsigned short* W,
               const float* bias, unsigned short* Ybf, int relu) {
    GemmJob j{};
    j.Xf = Xf; j.Asum = As; j.Asq = Aq; j.g = g; j.be = be;
    j.W = W; j.bias = bias; j.Ybf = Ybf; j.scale = 1.f; j.relu = relu;
    return j;
  };

  // L1: Wf GEMM + LN(enc)+dec stats+cast + early casts + uvec(+bf) + zero
  {
    Phase0Args pa{};
    pa.enc = enc; pa.g_ec = n_ec_g; pa.b_ec = n_ec_b; pa.f_n = f_n_b;
    pa.dec = dec; pa.md = md; pa.q2d = q2d; pa.dec_b = dec_b;
    pa.cast[0] = {ec_Wq, w_ecWq, W262, nullptr};
    pa.cast[1] = {ec_Wk, w_ecWkg, W262, n_dci_g};
    pa.cast[2] = {ec_Wv, w_ecWvg, W262, n_dci_g};
    pa.cast[3] = {pW, w_pW, W262, nullptr};
    pa.Wk = ec_Wk; pa.Wv = ec_Wv; pa.bk = ec_bk; pa.bv = ec_bv;
    pa.g_dci = n_dci_g; pa.b_dci = n_dci_b;
    pa.u_k = u_k; pa.u_v = u_v; pa.c_k = c_k; pa.c_v = c_v;
    pa.WoA = dc_Wo; pa.WvA = dc_Wv; pa.Wfb = w_Wf;
    pa.bv2 = dc_bv; pa.bo2 = dc_bo; pa.bf_out = bf;
    pa.zbase = stx; pa.zcount = 10240;
    phase0<<<2497, 256, 0, stream>>>(pa);
  }
  // L2: batch A (5 GEMMs: t[stats], Qe, Kd, Vd, Ed) BM=128 + casts (z=5,6)
  {
    GemmBatch gb{};
    gb.j[0] = J(f_n_b, w_Wf, bf, nullptr, nullptr, tb_b, 1.f, 0);
    gb.j[0].Ssum = t_s; gb.j[0].Ssq = t_sq;
    gb.j[1] = J(f_n_b, w_ecWq, ec_bq, nullptr, nullptr, Qe_b, 0.125f, 0);
    gb.j[2] = J(dec_b, w_ecWkg, nullptr, nullptr, nullptr, Kd_b, 1.f, 0);
    gb.j[3] = J(dec_b, w_ecWvg, nullptr, nullptr, nullptr, Vd_b, 1.f, 0);
    gb.j[4] = J(dec_b, w_pW, pWb, nullptr, Ed, nullptr, 1.f, 0);
    int pg = 0;
    auto addpages = [&](const float* s, unsigned short* d, int n) {
      for (int off = 0; off < n; off += W262) {
        gb.cp[pg].src = s + off;
        gb.cp[pg].dst = d + off;
        ++pg;
      }
    };
    addpages(ec_Wo, w_ecWo, W262);
    addpages(es_Wi, w_esWi, W786);
    addpages(ds_Wi, w_dsWi, W786);
    addpages(es_Wo, w_esWo, W262);
    addpages(ds_Wo, w_dsWo, W262);
    addpages(eff_W1, w_effW1, W1M);
    addpages(dff_W1, w_dffW1, W1M);
    addpages(eff_W2, w_effW2, W1M);
    addpages(dff_W2, w_dffW2, W1M);
    gb.cast_total = pg * W262;  // 25 * 262144 = 6553600
    gemm_bf16<1, false, true, 8, 128><<<dim3(8, 8, 7), 512, 0, stream>>>(
        gb, 1024, 512, 512, 5);
  }
  // L3: batch B (Kt, Vt, Et) + mr (per-(j,i,b) LN stats via MFMA) at z==3
  {
    GemmBatch gb{};
    gb.j[0] = J(tb_b, w_ecWkg, nullptr, nullptr, nullptr, Kt_b, 1.f, 0);
    gb.j[1] = J(tb_b, w_ecWvg, nullptr, nullptr, nullptr, Vt_b, 1.f, 0);
    gb.j[2] = J(tb_b, w_pW, pb, nullptr, Et, nullptr, 1.f, 0);
    gb.mr = {dec_b, tb_b, md, q2d, t_s, t_sq, mArr, rArr};
    gemm_bf16<2, false, false, 4, 64><<<dim3(8, 16, 4), 256, 0, stream>>>(
        gb, 1024, 512, 512, 3);
  }
  // L4: ec cross-attention (256 blocks x 128 thr, j-split)
  ec_attn<<<256, 128, 0, stream>>>(Qe_b, Kd_b, Kt_b, Vd_b, Vt_b, u_k, u_v, c_k,
                                   c_v, mArr, rArr, Oec_b);
  // L5: enc1 GEMM (z==0, with stats) + pooling (z=1..8 -> 1024 blocks)
  {
    GemmBatch gb{};
    gb.j[0] = J(Oec_b, w_ecWo, ec_bo, enc, enc1, nullptr, 1.f, 0);
    gb.j[0].Ssum = e1s; gb.j[0].Ssq = e1q;
    gb.pl = {Ed, Et, pv, dec, tb_b, dec1, d1s, d1q};
    gemm_bf16<3, false, true, 4, 64><<<dim3(8, 16, 9), 256, 0, stream>>>(
        gb, 1024, 512, 512, 1);
  }
  // L6: QKV projections with folded pre-norm (BM=128, NW=8)
  {
    GemmBatch gb{};
    gb.j[0] = JF(enc1, e1s, e1q, n_es_g, n_es_b, w_esWi, es_bi, QKVe_b, 0);
    gb.j[1] = JF(dec1, d1s, d1q, n_ds_g, n_ds_b, w_dsWi, ds_bi, QKVd_b, 0);
    gemm_bf16<0, true, false, 8, 128><<<dim3(24, 8, 2), 512, 0, stream>>>(
        gb, 1024, 1536, 512, -1);
  }
  // L7: self-attention cores (512 blocks x 128 thr, q-split)
  self_attn<<<dim3(128, 2, 2), 128, 0, stream>>>(QKVe_b, OaE, QKVd_b, OaD);
  // L8: output proj + residual + row stats (NW=8, BM=64)
  {
    GemmBatch gb{};
    gb.j[0] = J(OaE, w_esWo, es_bo, enc1, enc2, nullptr, 1.f, 0);
    gb.j[0].Ssum = e2s; gb.j[0].Ssq = e2q;
    gb.j[1] = J(OaD, w_dsWo, ds_bo, dec1, dec2, nullptr, 1.f, 0);
    gb.j[1].Ssum = d2s; gb.j[1].Ssq = d2q;
    gemm_bf16<0, false, true, 8, 64><<<dim3(8, 16, 2), 512, 0, stream>>>(
        gb, 1024, 512, 512, -1);
  }
  // L9: FFN layer 1 (relu) with folded pre-norm (BM=128, NW=8)
  {
    GemmBatch gb{};
    gb.j[0] = JF(enc2, e2s, e2q, n_ef_g, n_ef_b, w_effW1, eff_b1, He_b, 1);
    gb.j[1] = JF(dec2, d2s, d2q, n_df_g, n_df_b, w_dffW1, dff_b1, Hd_b, 1);
    gemm_bf16<0, true, false, 8, 128><<<dim3(32, 8, 2), 512, 0, stream>>>(
        gb, 1024, 2048, 512, -1);
  }
  // L10: FFN layer 2 + residual -> outputs (NW=8, BM=64)
  float* out = (float*)d_out;
  {
    GemmBatch gb{};
    gb.j[0] = J(He_b, w_effW2, eff_b2, enc2, out, nullptr, 1.f, 0);
    gb.j[1] = J(Hd_b, w_dffW2, dff_b2, dec2, out + U, nullptr, 1.f, 0);
    gemm_bf16<0, false, false, 8, 64><<<dim3(8, 16, 2), 512, 0, stream>>>(
        gb, 1024, 512, 2048, -1);
  }
}

// Round 7
// 284.531 us; speedup vs baseline: 1.0249x; 1.0249x over previous
//
#include <hip/hip_runtime.h>

// Problem constants: D=512, H=8 (hd=64), DFF=2048, NE=64, ND=64, B=16
// Identities exploited (carried from prior rounds):
//  - dc cross-attention has softmax over 1 key -> t[j,b] = Wo(Wv f_n[j,b]+bv)+bo
//  - G_fj[j,i,b] = dec[i,b] + t[j,b]  (rank-decomposed; never materialized)
//  - LN(G_fj) linearity: K/V projections & pooling energy decompose into
//    per-i and per-j 1024-row GEMMs + scalar stats m[j,i,b], r[j,i,b].
// R16: latency-chain fixes in the attention/pool family (the only kernels with
// a DIRECT slow measurement: R1 attnpool 48.7us @ 15.7% occ, all-low).
//  - ec_attn: hoist mArr/rArr (32 f32), Vt (16), u_v/c_v loads into registers
//    BEFORE the QK MFMA section (latency hides under MFMA/LDS instead of
//    serializing with the softmax chain). Same values, same math.
//  - pool: jl-loop unroll 1->4, j2-loop unroll 8->16 (more loads in flight).
//  GEMM structure unchanged (R13 NW8 + R15 BM128 both neutral -> GEMMs are
//  near their small-size envelope; launches ~1us each from R0->R2 slope).

typedef __bf16 bf16_t;
typedef bf16_t bf16x8 __attribute__((ext_vector_type(8)));
typedef float f32x4 __attribute__((ext_vector_type(4)));
typedef unsigned short u16x4 __attribute__((ext_vector_type(4)));
typedef unsigned short u16x8 __attribute__((ext_vector_type(8)));

__device__ inline unsigned short f2bf(float f) {
  unsigned int u = __float_as_uint(f);
  u += 0x7fffu + ((u >> 16) & 1u);  // RNE
  return (unsigned short)(u >> 16);
}
__device__ inline float bf2f(unsigned short u) {
  return __uint_as_float(((unsigned int)u) << 16);
}

__device__ inline float wsum(float v) {
#pragma unroll
  for (int o = 1; o < 64; o <<= 1) v += __shfl_xor(v, o);
  return v;
}
__device__ inline float wmax(float v) {
#pragma unroll
  for (int o = 1; o < 64; o <<= 1) v = fmaxf(v, __shfl_xor(v, o));
  return v;
}

struct CastJob {
  const float* src;
  unsigned short* dst;
  int n;
  const float* cs;  // per-(i & 511) scale or null
};
struct CastPage {
  const float* src;
  unsigned short* dst;
};

// ---------------- LN / stats bodies ----------------------------------------
__device__ inline void ln_body(const float* __restrict__ x,
                               const float* __restrict__ g,
                               const float* __restrict__ be,
                               unsigned short* __restrict__ y, int t) {
  float v0 = x[t], v1 = x[t + 256];
  float s = wsum(v0 + v1);
  float s2 = wsum(v0 * v0 + v1 * v1);
  __shared__ float sh[8];
  int w = t >> 6, lane = t & 63;
  if (lane == 0) { sh[w] = s; sh[4 + w] = s2; }
  __syncthreads();
  s = sh[0] + sh[1] + sh[2] + sh[3];
  s2 = sh[4] + sh[5] + sh[6] + sh[7];
  float mean = s * (1.f / 512.f);
  float var = s2 * (1.f / 512.f) - mean * mean;
  float r = rsqrtf(var + 1e-5f);
  y[t] = f2bf((v0 - mean) * r * g[t] + be[t]);
  y[t + 256] = f2bf((v1 - mean) * r * g[t + 256] + be[t + 256]);
}

__device__ inline void stats_body(const float* __restrict__ x,
                                  float* __restrict__ m, float* __restrict__ q2,
                                  unsigned short* __restrict__ xb, int t,
                                  int row) {
  float v0 = x[t], v1 = x[t + 256];
  if (xb) {
    xb[t] = f2bf(v0);
    xb[t + 256] = f2bf(v1);
  }
  float s = wsum(v0 + v1);
  float s2 = wsum(v0 * v0 + v1 * v1);
  __shared__ float sh2[8];
  int w = t >> 6, lane = t & 63;
  if (lane == 0) { sh2[w] = s; sh2[4 + w] = s2; }
  __syncthreads();
  if (t == 0) {
    s = sh2[0] + sh2[1] + sh2[2] + sh2[3];
    s2 = sh2[4] + sh2[5] + sh2[6] + sh2[7];
    m[row] = s * (1.f / 512.f);
    q2[row] = s2 * (1.f / 512.f);
  }
}

// ------- phase0: Wf GEMM + LN(enc)+dec stats + casts + uvec(+bf) + zero -----
struct Phase0Args {
  const float* enc; const float* g_ec; const float* b_ec; unsigned short* f_n;
  const float* dec; float* md; float* q2d; unsigned short* dec_b;
  CastJob cast[4];
  const float* Wk; const float* Wv; const float* bk; const float* bv;
  const float* g_dci; const float* b_dci;
  float* u_k; float* u_v; float* c_k; float* c_v;
  // Wf = WoA @ WvA (512x512x512), bf = WoA @ bv2 + bo2
  const float* WoA; const float* WvA; unsigned short* Wfb;
  const float* bv2; const float* bo2; float* bf_out;
  float* zbase; int zcount;
};

__global__ __launch_bounds__(256) void phase0(Phase0Args a) {
  __shared__ unsigned short WAs[64][72];
  __shared__ unsigned short WBs[64][72];
  int bx = blockIdx.x;
  const int t = threadIdx.x;
  if (bx < 64) {
    // Wf[n,k] = sum_m Wo[n,m] * Wv[m,k]  (bf16 MFMA, fp32 staged+cast)
    const int bm = (bx >> 3) * 64;   // n rows
    const int bn = (bx & 7) * 64;    // k cols
    const int lane = t & 63;
    const int wave = t >> 6;
    const int wr = wave >> 1;
    const int wc = wave & 1;
    const int fr = lane & 15;
    const int fg = lane >> 4;
    const int rr = t >> 2;
    const int c = (t & 3) * 16;
    f32x4 acc[2][2] = {};
    for (int m0 = 0; m0 < 512; m0 += 64) {
      const float* ap = a.WoA + (size_t)(bm + rr) * 512 + m0 + c;
      float4 a0 = *(const float4*)ap;
      float4 a1 = *(const float4*)(ap + 4);
      float4 a2 = *(const float4*)(ap + 8);
      float4 a3 = *(const float4*)(ap + 12);
      u16x8 lo = {f2bf(a0.x), f2bf(a0.y), f2bf(a0.z), f2bf(a0.w),
                  f2bf(a1.x), f2bf(a1.y), f2bf(a1.z), f2bf(a1.w)};
      u16x8 hi = {f2bf(a2.x), f2bf(a2.y), f2bf(a2.z), f2bf(a2.w),
                  f2bf(a3.x), f2bf(a3.y), f2bf(a3.z), f2bf(a3.w)};
      *(u16x8*)&WAs[rr][c] = lo;
      *(u16x8*)&WAs[rr][c + 8] = hi;
      const float* bp = a.WvA + (size_t)(m0 + rr) * 512 + bn + c;
      float4 b0 = *(const float4*)bp;
      float4 b1 = *(const float4*)(bp + 4);
      float4 b2 = *(const float4*)(bp + 8);
      float4 b3 = *(const float4*)(bp + 12);
      float bv16[16] = {b0.x, b0.y, b0.z, b0.w, b1.x, b1.y, b1.z, b1.w,
                        b2.x, b2.y, b2.z, b2.w, b3.x, b3.y, b3.z, b3.w};
#pragma unroll
      for (int jj = 0; jj < 16; ++jj) WBs[c + jj][rr] = f2bf(bv16[jj]);
      __syncthreads();
#pragma unroll
      for (int ks = 0; ks < 2; ++ks) {
        int kk = ks * 32 + fg * 8;
        bf16x8 fa0 = *(const bf16x8*)&WAs[wr * 32 + fr][kk];
        bf16x8 fa1 = *(const bf16x8*)&WAs[wr * 32 + 16 + fr][kk];
        bf16x8 fb0 = *(const bf16x8*)&WBs[wc * 32 + fr][kk];
        bf16x8 fb1 = *(const bf16x8*)&WBs[wc * 32 + 16 + fr][kk];
        acc[0][0] = __builtin_amdgcn_mfma_f32_16x16x32_bf16(fa0, fb0, acc[0][0], 0, 0, 0);
        acc[0][1] = __builtin_amdgcn_mfma_f32_16x16x32_bf16(fa0, fb1, acc[0][1], 0, 0, 0);
        acc[1][0] = __builtin_amdgcn_mfma_f32_16x16x32_bf16(fa1, fb0, acc[1][0], 0, 0, 0);
        acc[1][1] = __builtin_amdgcn_mfma_f32_16x16x32_bf16(fa1, fb1, acc[1][1], 0, 0, 0);
      }
      __syncthreads();
    }
#pragma unroll
    for (int mt = 0; mt < 2; ++mt) {
#pragma unroll
      for (int nt = 0; nt < 2; ++nt) {
        int col = bn + wc * 32 + nt * 16 + fr;
        int rowb = bm + wr * 32 + mt * 16 + fg * 4;
#pragma unroll
        for (int r = 0; r < 4; ++r) {
          a.Wfb[(size_t)(rowb + r) * 512 + col] = f2bf(acc[mt][nt][r]);
        }
      }
    }
    return;
  }
  bx -= 64;
  if (bx < 2048) {
    int row = bx;
    if (row < 1024) {
      ln_body(a.enc + (size_t)row * 512, a.g_ec, a.b_ec,
              a.f_n + (size_t)row * 512, t);
    } else {
      row -= 1024;
      stats_body(a.dec + (size_t)row * 512, a.md, a.q2d,
                 a.dec_b + (size_t)row * 512, t, row);
    }
    return;
  }
  bx -= 2048;
  if (bx < 256) {
    // early casts: 4 jobs x 262144 elems, single shot, 16 elems/thread
    int e = ((bx << 8) | t) << 4;
    int jj = e >> 18;
    int i = e & 262143;
    const CastJob cj = a.cast[jj];
    const float* s = cj.src + i;
    float4 v0 = *(const float4*)s;
    float4 v1 = *(const float4*)(s + 4);
    float4 v2 = *(const float4*)(s + 8);
    float4 v3 = *(const float4*)(s + 12);
    if (cj.cs) {
      int k = i & 511;
      float4 c0 = *(const float4*)(cj.cs + k);
      float4 c1 = *(const float4*)(cj.cs + k + 4);
      float4 c2 = *(const float4*)(cj.cs + k + 8);
      float4 c3 = *(const float4*)(cj.cs + k + 12);
      v0.x *= c0.x; v0.y *= c0.y; v0.z *= c0.z; v0.w *= c0.w;
      v1.x *= c1.x; v1.y *= c1.y; v1.z *= c1.z; v1.w *= c1.w;
      v2.x *= c2.x; v2.y *= c2.y; v2.z *= c2.z; v2.w *= c2.w;
      v3.x *= c3.x; v3.y *= c3.y; v3.z *= c3.z; v3.w *= c3.w;
    }
    u16x8 o0 = {f2bf(v0.x), f2bf(v0.y), f2bf(v0.z), f2bf(v0.w),
                f2bf(v1.x), f2bf(v1.y), f2bf(v1.z), f2bf(v1.w)};
    u16x8 o1 = {f2bf(v2.x), f2bf(v2.y), f2bf(v2.z), f2bf(v2.w),
                f2bf(v3.x), f2bf(v3.y), f2bf(v3.z), f2bf(v3.w)};
    *(u16x8*)(cj.dst + i) = o0;
    *(u16x8*)(cj.dst + i + 8) = o1;
    return;
  }
  bx -= 256;
  if (bx < 128) {
    int n = bx * 4 + (t >> 6);
    int lane = t & 63;
    const float* wk = a.Wk + (size_t)n * 512;
    const float* wv = a.Wv + (size_t)n * 512;
    const float* wo = a.WoA + (size_t)n * 512;
    float uk = 0.f, uv = 0.f, ck = 0.f, cv = 0.f, bfa = 0.f;
#pragma unroll
    for (int k0 = 0; k0 < 512; k0 += 64) {
      int k = k0 + lane;
      float x = wk[k], y = wv[k], gg = a.g_dci[k], bb = a.b_dci[k];
      uk += x * gg; ck += x * bb;
      uv += y * gg; cv += y * bb;
      bfa += wo[k] * a.bv2[k];
    }
    uk = wsum(uk); uv = wsum(uv); ck = wsum(ck); cv = wsum(cv);
    bfa = wsum(bfa);
    if (lane == 0) {
      a.u_k[n] = uk; a.u_v[n] = uv;
      a.c_k[n] = ck + a.bk[n]; a.c_v[n] = cv + a.bv[n];
      a.bf_out[n] = bfa + a.bo2[n];
    }
    return;
  }
  for (int i = t; i < a.zcount; i += 256) a.zbase[i] = 0.f;
}

// ---------------- unified batched bf16 MFMA GEMM ----------------------------
struct GemmJob {
  const unsigned short* X;   // bf16 A (when Xf==null)
  const float* Xf;           // fp32 A with fused LN (overrides X)
  const float* Asum; const float* Asq;  // per-row sum / sum-of-squares
  const float* g; const float* be;      // LN gamma/beta over K (=512)
  const unsigned short* W;
  const float* bias;
  const float* resid;
  float* Y;
  unsigned short* Ybf;
  float* Ssum; float* Ssq;   // epilogue row-stat accumulators (atomics)
  float scale;
  int relu;
};
struct MrJob {
  const unsigned short* A; const unsigned short* B;
  const float* md; const float* q2d;
  const float* ts; const float* tsq;   // raw sums (divide by 512)
  float* mArr; float* rArr;
};
struct PoolJob {
  const float* Ed; const float* Et; const float* pv; const float* dec;
  const unsigned short* tbf; float* dec1; float* d1s; float* d1q;
};
struct GemmBatch {
  GemmJob j[5];
  MrJob mr;
  CastPage cp[25];
  int cast_total;
  PoolJob pl;
};

__device__ inline u16x8 fold_pack(float4 va, float4 vb, const float* gp,
                                  const float* bp, float m, float ri) {
  float4 g0 = *(const float4*)gp;
  float4 g1 = *(const float4*)(gp + 4);
  float4 e0 = *(const float4*)bp;
  float4 e1 = *(const float4*)(bp + 4);
  u16x8 o;
  o[0] = f2bf((va.x - m) * ri * g0.x + e0.x);
  o[1] = f2bf((va.y - m) * ri * g0.y + e0.y);
  o[2] = f2bf((va.z - m) * ri * g0.z + e0.z);
  o[3] = f2bf((va.w - m) * ri * g0.w + e0.w);
  o[4] = f2bf((vb.x - m) * ri * g1.x + e1.x);
  o[5] = f2bf((vb.y - m) * ri * g1.y + e1.y);
  o[6] = f2bf((vb.z - m) * ri * g1.z + e1.z);
  o[7] = f2bf((vb.w - m) * ri * g1.w + e1.w);
  return o;
}

// Pool body: one block per (i,b); 256 threads.
__device__ void pool_body(const PoolJob& p, int i, int b) {
  __shared__ float esh[64], wsh[64], pps[8];
  const int t = threadIdx.x;
  int wave = t >> 6, lane = t & 63;
  float edv[8], pvv[8];
  const float* ed = p.Ed + (size_t)(i * 16 + b) * 512;
#pragma unroll
  for (int c = 0; c < 8; ++c) {
    edv[c] = ed[c * 64 + lane];
    pvv[c] = p.pv[c * 64 + lane];
  }
#pragma unroll 4
  for (int jl = 0; jl < 16; ++jl) {
    int j = wave * 16 + jl;
    const float* et = p.Et + (size_t)(j * 16 + b) * 512;
    float s = 0.f;
#pragma unroll
    for (int c = 0; c < 8; ++c) {
      float x = edv[c] + et[c * 64 + lane];
      float e2 = __expf(2.f * x);
      float th = 1.f - 2.f * __builtin_amdgcn_rcpf(e2 + 1.f);  // tanh
      s += th * pvv[c];
    }
    s = wsum(s);
    if (lane == 0) esh[j] = s;
  }
  __syncthreads();
  if (t < 64) {
    float e = esh[t];
    float mx = wmax(e);
    float ex = __expf(e - mx);
    float se = wsum(ex);
    wsh[t] = ex / se;
  }
  __syncthreads();
  size_t rowib = (size_t)(i * 16 + b) * 512;
  int d2 = t * 2;
  float2 dv = *(const float2*)(p.dec + rowib + d2);
  float acc0 = dv.x, acc1 = dv.y;
#pragma unroll 16
  for (int j2 = 0; j2 < 64; ++j2) {
    const unsigned short* tp = p.tbf + (size_t)(j2 * 16 + b) * 512 + d2;
    float w = wsh[j2];
    acc0 += w * bf2f(tp[0]);
    acc1 += w * bf2f(tp[1]);
  }
  float2 ov = {acc0, acc1};
  *(float2*)(p.dec1 + rowib + d2) = ov;
  float s1 = acc0 + acc1;
  float s2v = acc0 * acc0 + acc1 * acc1;
  s1 = wsum(s1);
  s2v = wsum(s2v);
  if (lane == 0) { pps[wave] = s1; pps[4 + wave] = s2v; }
  __syncthreads();
  if (t == 0) {
    p.d1s[i * 16 + b] = pps[0] + pps[1] + pps[2] + pps[3];
    p.d1q[i * 16 + b] = pps[4] + pps[5] + pps[6] + pps[7];
  }
}

// EXTRA: 0=none, 1=cast pages at z>=xz, 2=mr slice at z==xz, 3=pool at z>=xz
// NW: waves per block. BMT: A-tile rows (64 or 128; 128 requires NW=8).
//  NW4/BMT64 : wave-tile 32x32 (MT=2)   NW8/BMT64 : wave-tile 16x32 (MT=1)
//  NW8/BMT128: wave-tile 32x32 (MT=2), 64 MFMA/block/K-step
template <int EXTRA, bool FOLD, bool STATS, int NW, int BMT>
__global__ __launch_bounds__(NW * 64) void gemm_bf16(GemmBatch gb, int M,
                                                     int N, int K, int xz) {
  const int t = threadIdx.x;
  constexpr int NT = NW * 64;
  if constexpr (EXTRA == 1) {
    if ((int)blockIdx.z >= xz) {
      const int nbz = (int)(gridDim.x * gridDim.y);
      const int bid = ((int)blockIdx.z - xz) * nbz +
                      (int)blockIdx.y * (int)gridDim.x + (int)blockIdx.x;
      const int nthr = ((int)gridDim.z - xz) * nbz * NT;
      for (int base = (bid * NT + t) * 16; base < gb.cast_total;
           base += nthr * 16) {
        int page = base >> 18;
        int off = base & 262143;
        const float* s = gb.cp[page].src + off;
        unsigned short* d = gb.cp[page].dst + off;
        float4 v0 = *(const float4*)s;
        float4 v1 = *(const float4*)(s + 4);
        float4 v2 = *(const float4*)(s + 8);
        float4 v3 = *(const float4*)(s + 12);
        u16x8 o0 = {f2bf(v0.x), f2bf(v0.y), f2bf(v0.z), f2bf(v0.w),
                    f2bf(v1.x), f2bf(v1.y), f2bf(v1.z), f2bf(v1.w)};
        u16x8 o1 = {f2bf(v2.x), f2bf(v2.y), f2bf(v2.z), f2bf(v2.w),
                    f2bf(v3.x), f2bf(v3.y), f2bf(v3.z), f2bf(v3.w)};
        *(u16x8*)d = o0;
        *(u16x8*)(d + 8) = o1;
      }
      return;
    }
  }
  if constexpr (EXTRA == 3) {
    if ((int)blockIdx.z >= xz) {
      int pb = ((int)blockIdx.z - xz) * (int)(gridDim.x * gridDim.y) +
               (int)blockIdx.y * (int)gridDim.x + (int)blockIdx.x;
      pool_body(gb.pl, pb & 63, pb >> 6);
      return;
    }
  }
  __shared__ unsigned short As[BMT][72];  // 144B stride = 9x16B aligned
  __shared__ unsigned short Bs[64][72];
  const int lane = t & 63;
  const int wave = t >> 6;
  const int wr = wave >> 1;  // NW4: 0..1; NW8: 0..3
  const int wc = wave & 1;
  const int fr = lane & 15;
  const int fg = lane >> 4;
  constexpr int MT = (NW == 4 || BMT == 128) ? 2 : 1;
  constexpr int RB = MT * 16;  // wave row-band size
  const int r0 = t >> 3, o0 = (t & 7) * 8;
  const int r1 = ((t + 256) >> 3) & 63, o1 = ((t + 256) & 7) * 8;

  if constexpr (EXTRA == 2) {
    if ((int)blockIdx.z == xz) {
      // per-(j,i,b) LN stats via MFMA: S[i][j] = dec_b[i,b,:]·tb_b[j,b,:]
      const int bb = blockIdx.y * gridDim.x + blockIdx.x;
      if (bb >= 16) return;
      const unsigned short* Ap = gb.mr.A + (size_t)bb * 512;
      const unsigned short* Bp = gb.mr.B + (size_t)bb * 512;
      f32x4 acc[2][2] = {};
      for (int k0 = 0; k0 < 512; k0 += 64) {
        *(u16x8*)&As[r0][o0] = *(const u16x8*)&Ap[(size_t)r0 * 8192 + k0 + o0];
        *(u16x8*)&As[r1][o1] = *(const u16x8*)&Ap[(size_t)r1 * 8192 + k0 + o1];
        *(u16x8*)&Bs[r0][o0] = *(const u16x8*)&Bp[(size_t)r0 * 8192 + k0 + o0];
        *(u16x8*)&Bs[r1][o1] = *(const u16x8*)&Bp[(size_t)r1 * 8192 + k0 + o1];
        __syncthreads();
#pragma unroll
        for (int ks = 0; ks < 2; ++ks) {
          int kk = ks * 32 + fg * 8;
          bf16x8 a0 = *(const bf16x8*)&As[wr * 32 + fr][kk];
          bf16x8 a1 = *(const bf16x8*)&As[wr * 32 + 16 + fr][kk];
          bf16x8 b0 = *(const bf16x8*)&Bs[wc * 32 + fr][kk];
          bf16x8 b1 = *(const bf16x8*)&Bs[wc * 32 + 16 + fr][kk];
          acc[0][0] = __builtin_amdgcn_mfma_f32_16x16x32_bf16(a0, b0, acc[0][0], 0, 0, 0);
          acc[0][1] = __builtin_amdgcn_mfma_f32_16x16x32_bf16(a0, b1, acc[0][1], 0, 0, 0);
          acc[1][0] = __builtin_amdgcn_mfma_f32_16x16x32_bf16(a1, b0, acc[1][0], 0, 0, 0);
          acc[1][1] = __builtin_amdgcn_mfma_f32_16x16x32_bf16(a1, b1, acc[1][1], 0, 0, 0);
        }
        __syncthreads();
      }
#pragma unroll
      for (int nt = 0; nt < 2; ++nt) {
        int j = wc * 32 + nt * 16 + fr;
        float mtv = gb.mr.ts[j * 16 + bb] * (1.f / 512.f);
        float qtv = gb.mr.tsq[j * 16 + bb] * (1.f / 512.f);
#pragma unroll
        for (int mt = 0; mt < 2; ++mt) {
          int ibase = wr * 32 + mt * 16 + fg * 4;
#pragma unroll
          for (int r = 0; r < 4; ++r) {
            int i = ibase + r;
            float s = acc[mt][nt][r];
            float mean = gb.mr.md[i * 16 + bb] + mtv;
            float msq = gb.mr.q2d[i * 16 + bb] + qtv + s * (2.f / 512.f);
            int idx = bb * 4096 + j * 64 + i;
            gb.mr.mArr[idx] = mean;
            gb.mr.rArr[idx] = rsqrtf(msq - mean * mean + 1e-5f);
          }
        }
      }
      return;
    }
  }

  const GemmJob jb = gb.j[blockIdx.z];
  const int bm = blockIdx.y * BMT;
  const int bn = blockIdx.x * 64;
  f32x4 acc[MT][2] = {};
  const unsigned short* Wp = jb.W + (size_t)bn * K;
  // second A-row for each staging scheme
  const int ra = (NW == 4) ? r1 : r0 + 64;   // (BMT==128 uses r0+64)
  const int oa = (NW == 4) ? o1 : o0;

  u16x8 xa0, xa1;
  float4 fa0a, fa0b, fa1a, fa1b;
  float lm0 = 0.f, lr0i = 0.f, lm1 = 0.f, lr1i = 0.f;
  const unsigned short* Xp = nullptr;
  constexpr bool A2 = (NW == 4) || (BMT == 128);  // two A loads per thread
  if constexpr (FOLD) {
    float s = jb.Asum[bm + r0], q = jb.Asq[bm + r0];
    lm0 = s * (1.f / 512.f);
    lr0i = rsqrtf(q * (1.f / 512.f) - lm0 * lm0 + 1e-5f);
    if constexpr (A2) {
      s = jb.Asum[bm + ra]; q = jb.Asq[bm + ra];
      lm1 = s * (1.f / 512.f);
      lr1i = rsqrtf(q * (1.f / 512.f) - lm1 * lm1 + 1e-5f);
    }
    const float* p0 = jb.Xf + (size_t)(bm + r0) * K + o0;
    fa0a = *(const float4*)p0; fa0b = *(const float4*)(p0 + 4);
    if constexpr (A2) {
      const float* p1 = jb.Xf + (size_t)(bm + ra) * K + oa;
      fa1a = *(const float4*)p1; fa1b = *(const float4*)(p1 + 4);
    }
  } else {
    Xp = jb.X + (size_t)bm * K;
    xa0 = *(const u16x8*)&Xp[(size_t)r0 * K + o0];
    if constexpr (A2) xa1 = *(const u16x8*)&Xp[(size_t)ra * K + oa];
  }
  u16x8 wa0 = *(const u16x8*)&Wp[(size_t)r0 * K + o0];
  u16x8 wa1;
  if constexpr (NW == 4) wa1 = *(const u16x8*)&Wp[(size_t)r1 * K + o1];

  for (int k0 = 0; k0 < K; k0 += 64) {
    if constexpr (FOLD) {
      *(u16x8*)&As[r0][o0] = fold_pack(fa0a, fa0b, jb.g + k0 + o0, jb.be + k0 + o0, lm0, lr0i);
      if constexpr (A2)
        *(u16x8*)&As[ra][oa] = fold_pack(fa1a, fa1b, jb.g + k0 + oa, jb.be + k0 + oa, lm1, lr1i);
    } else {
      *(u16x8*)&As[r0][o0] = xa0;
      if constexpr (A2) *(u16x8*)&As[ra][oa] = xa1;
    }
    *(u16x8*)&Bs[r0][o0] = wa0;
    if constexpr (NW == 4) *(u16x8*)&Bs[r1][o1] = wa1;
    __syncthreads();
    if (k0 + 64 < K) {
      const int kn = k0 + 64;
      if constexpr (FOLD) {
        const float* p0 = jb.Xf + (size_t)(bm + r0) * K + kn + o0;
        fa0a = *(const float4*)p0; fa0b = *(const float4*)(p0 + 4);
        if constexpr (A2) {
          const float* p1 = jb.Xf + (size_t)(bm + ra) * K + kn + oa;
          fa1a = *(const float4*)p1; fa1b = *(const float4*)(p1 + 4);
        }
      } else {
        xa0 = *(const u16x8*)&Xp[(size_t)r0 * K + kn + o0];
        if constexpr (A2) xa1 = *(const u16x8*)&Xp[(size_t)ra * K + kn + oa];
      }
      wa0 = *(const u16x8*)&Wp[(size_t)r0 * K + kn + o0];
      if constexpr (NW == 4) wa1 = *(const u16x8*)&Wp[(size_t)r1 * K + kn + o1];
    }
#pragma unroll
    for (int ks = 0; ks < 2; ++ks) {
      int kk = ks * 32 + fg * 8;
      bf16x8 b0 = *(const bf16x8*)&Bs[wc * 32 + fr][kk];
      bf16x8 b1 = *(const bf16x8*)&Bs[wc * 32 + 16 + fr][kk];
      if constexpr (MT == 2) {
        bf16x8 a0 = *(const bf16x8*)&As[wr * 32 + fr][kk];
        bf16x8 a1 = *(const bf16x8*)&As[wr * 32 + 16 + fr][kk];
        acc[0][0] = __builtin_amdgcn_mfma_f32_16x16x32_bf16(a0, b0, acc[0][0], 0, 0, 0);
        acc[0][1] = __builtin_amdgcn_mfma_f32_16x16x32_bf16(a0, b1, acc[0][1], 0, 0, 0);
        acc[1][0] = __builtin_amdgcn_mfma_f32_16x16x32_bf16(a1, b0, acc[1][0], 0, 0, 0);
        acc[1][1] = __builtin_amdgcn_mfma_f32_16x16x32_bf16(a1, b1, acc[1][1], 0, 0, 0);
      } else {
        bf16x8 a0 = *(const bf16x8*)&As[wr * 16 + fr][kk];
        acc[0][0] = __builtin_amdgcn_mfma_f32_16x16x32_bf16(a0, b0, acc[0][0], 0, 0, 0);
        acc[0][1] = __builtin_amdgcn_mfma_f32_16x16x32_bf16(a0, b1, acc[0][1], 0, 0, 0);
      }
    }
    __syncthreads();
  }
  float rsum[MT][4], rsq[MT][4];
  if constexpr (STATS) {
#pragma unroll
    for (int mt = 0; mt < MT; ++mt)
#pragma unroll
      for (int r = 0; r < 4; ++r) { rsum[mt][r] = 0.f; rsq[mt][r] = 0.f; }
  }
#pragma unroll
  for (int mt = 0; mt < MT; ++mt) {
#pragma unroll
    for (int nt = 0; nt < 2; ++nt) {
      int col = bn + wc * 32 + nt * 16 + fr;
      int rowb = bm + wr * RB + mt * 16 + fg * 4;
      float bia = jb.bias ? jb.bias[col] : 0.f;
#pragma unroll
      for (int r = 0; r < 4; ++r) {
        float v = (acc[mt][nt][r] + bia) * jb.scale;
        if (jb.relu) v = fmaxf(v, 0.f);
        if (jb.resid) v += jb.resid[(size_t)(rowb + r) * N + col];
        size_t idx = (size_t)(rowb + r) * N + col;
        if (jb.Y) jb.Y[idx] = v;
        if (jb.Ybf) jb.Ybf[idx] = f2bf(v);
        if constexpr (STATS) { rsum[mt][r] += v; rsq[mt][r] += v * v; }
      }
    }
  }
  if constexpr (STATS) {
    if (jb.Ssum) {
#pragma unroll
      for (int mt = 0; mt < MT; ++mt)
#pragma unroll
        for (int r = 0; r < 4; ++r) {
          float s = rsum[mt][r], q = rsq[mt][r];
#pragma unroll
          for (int o = 1; o < 16; o <<= 1) {
            s += __shfl_xor(s, o);
            q += __shfl_xor(q, o);
          }
          if (fr == 0) {
            int row = bm + wr * RB + mt * 16 + fg * 4 + r;
            atomicAdd(&jb.Ssum[row], s);
            atomicAdd(&jb.Ssq[row], q);
          }
        }
    }
  }
}

// ------- ec cross-attention: 256 blocks x 128 thr, j-split, hoisted loads ---
__global__ __launch_bounds__(128) void ec_attn(
    const unsigned short* __restrict__ Qe, const unsigned short* __restrict__ Kd,
    const unsigned short* __restrict__ Kt, const unsigned short* __restrict__ Vd,
    const unsigned short* __restrict__ Vt, const float* __restrict__ u_k,
    const float* __restrict__ u_v, const float* __restrict__ c_k,
    const float* __restrict__ c_v, const float* __restrict__ mArr,
    const float* __restrict__ rArr, unsigned short* __restrict__ O) {
  int bx = blockIdx.x;
  int h = bx & 7;
  int b = (bx >> 3) & 15;
  int jlo = (bx >> 7) * 32;
  __shared__ unsigned short Qs[32][72];
  __shared__ unsigned short Ks[64][72];
  __shared__ unsigned short VdT[64][72];
  __shared__ unsigned short Ps[32][72];
  __shared__ float stp[32][4], sup[32][4], scp[32][4];
  __shared__ float stv[32], suv[32], scv[32], swv[32], swmv[32];
  int t = threadIdx.x;
  int wave = t >> 6, lane = t & 63;
  int fr = lane & 15, fg = lane >> 4;
  {
    int row = t >> 2;         // 0..31
    int qt = t & 3;
    int cb = qt * 16;
    size_t base = (size_t)((jlo + row) * 16 + b) * 512 + h * 64 + cb;
    u16x8 q0 = *(const u16x8*)(Qe + base);
    u16x8 q1 = *(const u16x8*)(Qe + base + 8);
    u16x8 kt0 = *(const u16x8*)(Kt + base);
    u16x8 kt1 = *(const u16x8*)(Kt + base + 8);
    *(u16x8*)&Qs[row][cb] = q0;
    *(u16x8*)&Qs[row][cb + 8] = q1;
    float st_ = 0.f, su_ = 0.f, sc_ = 0.f;
#pragma unroll
    for (int jj = 0; jj < 8; ++jj) {
      float qa = bf2f(q0[jj]), qb = bf2f(q1[jj]);
      st_ += qa * bf2f(kt0[jj]) + qb * bf2f(kt1[jj]);
      su_ += qa * u_k[h * 64 + cb + jj] + qb * u_k[h * 64 + cb + 8 + jj];
      sc_ += qa * c_k[h * 64 + cb + jj] + qb * c_k[h * 64 + cb + 8 + jj];
    }
    stp[row][qt] = st_;
    sup[row][qt] = su_;
    scp[row][qt] = sc_;
    int row2 = t >> 1;        // 0..63
    int c0 = (t & 1) * 32;
    size_t base2 = (size_t)(row2 * 16 + b) * 512 + h * 64 + c0;
    u16x8 k0 = *(const u16x8*)(Kd + base2);
    u16x8 k1 = *(const u16x8*)(Kd + base2 + 8);
    u16x8 k2 = *(const u16x8*)(Kd + base2 + 16);
    u16x8 k3 = *(const u16x8*)(Kd + base2 + 24);
    u16x8 v0 = *(const u16x8*)(Vd + base2);
    u16x8 v1 = *(const u16x8*)(Vd + base2 + 8);
    u16x8 v2 = *(const u16x8*)(Vd + base2 + 16);
    u16x8 v3 = *(const u16x8*)(Vd + base2 + 24);
    *(u16x8*)&Ks[row2][c0] = k0;
    *(u16x8*)&Ks[row2][c0 + 8] = k1;
    *(u16x8*)&Ks[row2][c0 + 16] = k2;
    *(u16x8*)&Ks[row2][c0 + 24] = k3;
#pragma unroll
    for (int jj = 0; jj < 8; ++jj) VdT[c0 + jj][row2] = v0[jj];
#pragma unroll
    for (int jj = 0; jj < 8; ++jj) VdT[c0 + 8 + jj][row2] = v1[jj];
#pragma unroll
    for (int jj = 0; jj < 8; ++jj) VdT[c0 + 16 + jj][row2] = v2[jj];
#pragma unroll
    for (int jj = 0; jj < 8; ++jj) VdT[c0 + 24 + jj][row2] = v3[jj];
  }
  // Hoisted latency-bound loads: issue BEFORE the barriers/MFMA so their
  // ~300cy L2 latency hides under staging + MFMA instead of serializing
  // with the softmax chain. Same values, same math.
  float mv[4][4], rv[4][4], vtv[4][4], uvv[4], cvv[4];
#pragma unroll
  for (int r = 0; r < 4; ++r) {
    int gj = jlo + wave * 16 + fg * 4 + r;
    const float* mrow = mArr + (size_t)b * 4096 + gj * 64;
    const float* rrow = rArr + (size_t)b * 4096 + gj * 64;
#pragma unroll
    for (int c = 0; c < 4; ++c) {
      mv[r][c] = mrow[c * 16 + fr];
      rv[r][c] = rrow[c * 16 + fr];
    }
  }
#pragma unroll
  for (int nt = 0; nt < 4; ++nt) {
    int d = nt * 16 + fr;
    uvv[nt] = u_v[h * 64 + d];
    cvv[nt] = c_v[h * 64 + d];
#pragma unroll
    for (int r = 0; r < 4; ++r) {
      int gj = jlo + wave * 16 + fg * 4 + r;
      vtv[nt][r] = bf2f(Vt[(size_t)(gj * 16 + b) * 512 + h * 64 + d]);
    }
  }
  __syncthreads();
  if (t < 32) {
    stv[t] = stp[t][0] + stp[t][1] + stp[t][2] + stp[t][3];
    suv[t] = sup[t][0] + sup[t][1] + sup[t][2] + sup[t][3];
    scv[t] = scp[t][0] + scp[t][1] + scp[t][2] + scp[t][3];
  }
  __syncthreads();
  f32x4 sacc[4] = {};
  bf16x8 aq0 = *(const bf16x8*)&Qs[wave * 16 + fr][fg * 8];
  bf16x8 aq1 = *(const bf16x8*)&Qs[wave * 16 + fr][32 + fg * 8];
#pragma unroll
  for (int nt = 0; nt < 4; ++nt) {
    bf16x8 b0 = *(const bf16x8*)&Ks[nt * 16 + fr][fg * 8];
    bf16x8 b1 = *(const bf16x8*)&Ks[nt * 16 + fr][32 + fg * 8];
    sacc[nt] = __builtin_amdgcn_mfma_f32_16x16x32_bf16(aq0, b0, sacc[nt], 0, 0, 0);
    sacc[nt] = __builtin_amdgcn_mfma_f32_16x16x32_bf16(aq1, b1, sacc[nt], 0, 0, 0);
  }
#pragma unroll
  for (int r = 0; r < 4; ++r) {
    int lj = wave * 16 + fg * 4 + r;
    float stj = stv[lj], suj = suv[lj], scj = scv[lj];
    float a0 = rv[r][0] * (sacc[0][r] + stj - mv[r][0] * suj) + scj;
    float a1 = rv[r][1] * (sacc[1][r] + stj - mv[r][1] * suj) + scj;
    float a2 = rv[r][2] * (sacc[2][r] + stj - mv[r][2] * suj) + scj;
    float a3 = rv[r][3] * (sacc[3][r] + stj - mv[r][3] * suj) + scj;
    float mx = fmaxf(fmaxf(a0, a1), fmaxf(a2, a3));
#pragma unroll
    for (int o = 1; o < 16; o <<= 1) mx = fmaxf(mx, __shfl_xor(mx, o));
    a0 = __expf(a0 - mx);
    a1 = __expf(a1 - mx);
    a2 = __expf(a2 - mx);
    a3 = __expf(a3 - mx);
    float se = a0 + a1 + a2 + a3;
#pragma unroll
    for (int o = 1; o < 16; o <<= 1) se += __shfl_xor(se, o);
    float inv = 1.f / se;
    float w0 = a0 * inv * rv[r][0];
    float w1 = a1 * inv * rv[r][1];
    float w2 = a2 * inv * rv[r][2];
    float w3 = a3 * inv * rv[r][3];
    float sw = w0 + w1 + w2 + w3;
    float swm = w0 * mv[r][0] + w1 * mv[r][1] + w2 * mv[r][2] + w3 * mv[r][3];
#pragma unroll
    for (int o = 1; o < 16; o <<= 1) {
      sw += __shfl_xor(sw, o);
      swm += __shfl_xor(swm, o);
    }
    Ps[lj][fr] = f2bf(w0);
    Ps[lj][16 + fr] = f2bf(w1);
    Ps[lj][32 + fr] = f2bf(w2);
    Ps[lj][48 + fr] = f2bf(w3);
    if (fr == 0) {
      swv[lj] = sw;
      swmv[lj] = swm;
    }
  }
  f32x4 oc[4] = {};
  bf16x8 ap0 = *(const bf16x8*)&Ps[wave * 16 + fr][fg * 8];
  bf16x8 ap1 = *(const bf16x8*)&Ps[wave * 16 + fr][32 + fg * 8];
#pragma unroll
  for (int nt = 0; nt < 4; ++nt) {
    bf16x8 b0 = *(const bf16x8*)&VdT[nt * 16 + fr][fg * 8];
    bf16x8 b1 = *(const bf16x8*)&VdT[nt * 16 + fr][32 + fg * 8];
    oc[nt] = __builtin_amdgcn_mfma_f32_16x16x32_bf16(ap0, b0, oc[nt], 0, 0, 0);
    oc[nt] = __builtin_amdgcn_mfma_f32_16x16x32_bf16(ap1, b1, oc[nt], 0, 0, 0);
  }
#pragma unroll
  for (int nt = 0; nt < 4; ++nt) {
    int d = nt * 16 + fr;
#pragma unroll
    for (int r = 0; r < 4; ++r) {
      int lj = wave * 16 + fg * 4 + r;
      int gj = jlo + lj;
      size_t gidx = (size_t)(gj * 16 + b) * 512 + h * 64 + d;
      float o = oc[nt][r] + swv[lj] * vtv[nt][r] - swmv[lj] * uvv[nt] + cvv[nt];
      O[gidx] = f2bf(o);
    }
  }
}

// ------- MFMA self-attention: 512 blocks x 128 thr (q-split) ----------------
__global__ __launch_bounds__(128) void self_attn(
    const unsigned short* __restrict__ QKVe, unsigned short* __restrict__ Oe,
    const unsigned short* __restrict__ QKVd, unsigned short* __restrict__ Od) {
  const unsigned short* QKV = blockIdx.z ? QKVd : QKVe;
  unsigned short* O = blockIdx.z ? Od : Oe;
  int h = blockIdx.x & 7;
  int b = blockIdx.x >> 3;
  int qlo = blockIdx.y * 32;
  __shared__ unsigned short Qs[32][72];
  __shared__ unsigned short Ksh[64][72];
  __shared__ unsigned short VT[64][72];
  __shared__ unsigned short Ps[32][72];
  int t = threadIdx.x;
  {
    int row = t >> 2;        // 0..31 (our q rows)
    int cb = (t & 3) * 16;
    const unsigned short* src =
        QKV + (size_t)((qlo + row) * 16 + b) * 1536 + h * 64 + cb;
    u16x8 q0 = *(const u16x8*)(src);
    u16x8 q1 = *(const u16x8*)(src + 8);
    *(u16x8*)&Qs[row][cb] = q0;
    *(u16x8*)&Qs[row][cb + 8] = q1;
    int row2 = t >> 1;       // 0..63 (all kv rows)
    int c0 = (t & 1) * 32;
    const unsigned short* src2 =
        QKV + (size_t)(row2 * 16 + b) * 1536 + h * 64 + c0;
    u16x8 k0 = *(const u16x8*)(src2 + 512);
    u16x8 k1 = *(const u16x8*)(src2 + 520);
    u16x8 k2 = *(const u16x8*)(src2 + 528);
    u16x8 k3 = *(const u16x8*)(src2 + 536);
    u16x8 v0 = *(const u16x8*)(src2 + 1024);
    u16x8 v1 = *(const u16x8*)(src2 + 1032);
    u16x8 v2 = *(const u16x8*)(src2 + 1040);
    u16x8 v3 = *(const u16x8*)(src2 + 1048);
    *(u16x8*)&Ksh[row2][c0] = k0;
    *(u16x8*)&Ksh[row2][c0 + 8] = k1;
    *(u16x8*)&Ksh[row2][c0 + 16] = k2;
    *(u16x8*)&Ksh[row2][c0 + 24] = k3;
#pragma unroll
    for (int jj = 0; jj < 8; ++jj) VT[c0 + jj][row2] = v0[jj];
#pragma unroll
    for (int jj = 0; jj < 8; ++jj) VT[c0 + 8 + jj][row2] = v1[jj];
#pragma unroll
    for (int jj = 0; jj < 8; ++jj) VT[c0 + 16 + jj][row2] = v2[jj];
#pragma unroll
    for (int jj = 0; jj < 8; ++jj) VT[c0 + 24 + jj][row2] = v3[jj];
  }
  __syncthreads();
  int wave = t >> 6, lane = t & 63;
  int fr = lane & 15, fg = lane >> 4;
  f32x4 sc[4] = {};
  bf16x8 aq0 = *(const bf16x8*)&Qs[wave * 16 + fr][fg * 8];
  bf16x8 aq1 = *(const bf16x8*)&Qs[wave * 16 + fr][32 + fg * 8];
#pragma unroll
  for (int nt = 0; nt < 4; ++nt) {
    bf16x8 b0 = *(const bf16x8*)&Ksh[nt * 16 + fr][fg * 8];
    bf16x8 b1 = *(const bf16x8*)&Ksh[nt * 16 + fr][32 + fg * 8];
    sc[nt] = __builtin_amdgcn_mfma_f32_16x16x32_bf16(aq0, b0, sc[nt], 0, 0, 0);
    sc[nt] = __builtin_amdgcn_mfma_f32_16x16x32_bf16(aq1, b1, sc[nt], 0, 0, 0);
  }
#pragma unroll
  for (int r = 0; r < 4; ++r) {
    float a0 = sc[0][r] * 0.125f, a1 = sc[1][r] * 0.125f;
    float a2 = sc[2][r] * 0.125f, a3 = sc[3][r] * 0.125f;
    float mx = fmaxf(fmaxf(a0, a1), fmaxf(a2, a3));
#pragma unroll
    for (int o = 1; o < 16; o <<= 1) mx = fmaxf(mx, __shfl_xor(mx, o));
    a0 = __expf(a0 - mx);
    a1 = __expf(a1 - mx);
    a2 = __expf(a2 - mx);
    a3 = __expf(a3 - mx);
    float se = a0 + a1 + a2 + a3;
#pragma unroll
    for (int o = 1; o < 16; o <<= 1) se += __shfl_xor(se, o);
    float inv = 1.f / se;
    int prow = wave * 16 + fg * 4 + r;
    Ps[prow][0 + fr] = f2bf(a0 * inv);
    Ps[prow][16 + fr] = f2bf(a1 * inv);
    Ps[prow][32 + fr] = f2bf(a2 * inv);
    Ps[prow][48 + fr] = f2bf(a3 * inv);
  }
  f32x4 oc[4] = {};
  bf16x8 ap0 = *(const bf16x8*)&Ps[wave * 16 + fr][fg * 8];
  bf16x8 ap1 = *(const bf16x8*)&Ps[wave * 16 + fr][32 + fg * 8];
#pragma unroll
  for (int nt = 0; nt < 4; ++nt) {
    bf16x8 b0 = *(const bf16x8*)&VT[nt * 16 + fr][fg * 8];
    bf16x8 b1 = *(const bf16x8*)&VT[nt * 16 + fr][32 + fg * 8];
    oc[nt] = __builtin_amdgcn_mfma_f32_16x16x32_bf16(ap0, b0, oc[nt], 0, 0, 0);
    oc[nt] = __builtin_amdgcn_mfma_f32_16x16x32_bf16(ap1, b1, oc[nt], 0, 0, 0);
  }
#pragma unroll
  for (int nt = 0; nt < 4; ++nt) {
#pragma unroll
    for (int r = 0; r < 4; ++r) {
      int q = qlo + wave * 16 + fg * 4 + r;
      int d = nt * 16 + fr;
      O[(size_t)(q * 16 + b) * 512 + h * 64 + d] = f2bf(oc[nt][r]);
    }
  }
}

extern "C" void kernel_launch(void* const* d_in, const int* in_sizes, int n_in,
                              void* d_out, int out_size, void* d_ws,
                              size_t ws_size, hipStream_t stream) {
  const float* enc = (const float*)d_in[0];
  const float* dec = (const float*)d_in[1];
  const float* ec_Wi = (const float*)d_in[2];
  const float* ec_bi = (const float*)d_in[3];
  const float* ec_Wo = (const float*)d_in[4];
  const float* ec_bo = (const float*)d_in[5];
  const float* dc_Wi = (const float*)d_in[6];
  const float* dc_bi = (const float*)d_in[7];
  const float* dc_Wo = (const float*)d_in[8];
  const float* dc_bo = (const float*)d_in[9];
  const float* es_Wi = (const float*)d_in[10];
  const float* es_bi = (const float*)d_in[11];
  const float* es_Wo = (const float*)d_in[12];
  const float* es_bo = (const float*)d_in[13];
  const float* ds_Wi = (const float*)d_in[14];
  const float* ds_bi = (const float*)d_in[15];
  const float* ds_Wo = (const float*)d_in[16];
  const float* ds_bo = (const float*)d_in[17];
  const float* eff_W1 = (const float*)d_in[18];
  const float* eff_b1 = (const float*)d_in[19];
  const float* eff_W2 = (const float*)d_in[20];
  const float* eff_b2 = (const float*)d_in[21];
  const float* dff_W1 = (const float*)d_in[22];
  const float* dff_b1 = (const float*)d_in[23];
  const float* dff_W2 = (const float*)d_in[24];
  const float* dff_b2 = (const float*)d_in[25];
  const float* n_ec_g = (const float*)d_in[26];
  const float* n_ec_b = (const float*)d_in[27];
  const float* n_es_g = (const float*)d_in[28];
  const float* n_es_b = (const float*)d_in[29];
  const float* n_ef_g = (const float*)d_in[30];
  const float* n_ef_b = (const float*)d_in[31];
  const float* n_dci_g = (const float*)d_in[34];
  const float* n_dci_b = (const float*)d_in[35];
  const float* n_ds_g = (const float*)d_in[36];
  const float* n_ds_b = (const float*)d_in[37];
  const float* n_df_g = (const float*)d_in[38];
  const float* n_df_b = (const float*)d_in[39];
  const float* pW = (const float*)d_in[40];
  const float* pWb = (const float*)d_in[41];
  const float* pv = (const float*)d_in[42];
  const float* pb = (const float*)d_in[43];

  float* ws = (float*)d_ws;
  const size_t U = 524288;  // 1024*512 elements
  float* Ed = ws + 3 * U;
  float* Et = ws + 7 * U;
  float* enc1 = ws + 8 * U;
  float* dec1 = ws + 9 * U;
  float* enc2 = ws + 10 * U;
  float* dec2 = ws + 11 * U;
  float* sm = ws + 12 * U;
  float* md = sm;
  float* q2d = sm + 1024;
  float* bf = sm + 2048;       // t bias = dc_Wo@dc_bv + dc_bo (512)
  float* u_k = sm + 4096;
  float* u_v = sm + 4608;
  float* c_k = sm + 5120;
  float* c_v = sm + 5632;
  float* mArr = sm + 6144;  // b-major [b][j][i], 65536
  float* rArr = sm + 6144 + 65536;
  // atomic / plain row-stat accumulators (fresh region, zeroed in phase0)
  float* stx = ws + 24 * U;
  float* t_s = stx;            // t row sums
  float* t_sq = stx + 1024;
  float* e1s = stx + 2048;     // enc1
  float* e1q = stx + 3072;
  float* d1s = stx + 4096;     // dec1 (plain store from pool)
  float* d1q = stx + 5120;
  float* e2s = stx + 6144;     // enc2
  float* e2q = stx + 7168;
  float* d2s = stx + 8192;     // dec2
  float* d2q = stx + 9216;
  unsigned short* ub0 = (unsigned short*)ws;
  unsigned short* Qe_b = ub0 + 0 * U;
  unsigned short* Kd_b = ub0 + 1 * U;
  unsigned short* Vd_b = ub0 + 2 * U;
  unsigned short* Kt_b = ub0 + 3 * U;
  unsigned short* Vt_b = ub0 + 4 * U;
  unsigned short* ub = (unsigned short*)(ws + 12 * U + 137216);
  const int W262 = 262144, W786 = 786432, W1M = 1048576;
  unsigned short* w_Wf = ub;            // composite dc_Wo @ dc_Wv (bf16)
  unsigned short* w_ecWq = w_Wf + W262;
  unsigned short* w_ecWkg = w_ecWq + W262;
  unsigned short* w_ecWvg = w_ecWkg + W262;
  unsigned short* w_pW = w_ecWvg + W262;
  unsigned short* w_unused = w_pW + W262;
  unsigned short* w_ecWo = w_unused + W262;
  unsigned short* w_esWi = w_ecWo + W262;
  unsigned short* w_dsWi = w_esWi + W786;
  unsigned short* w_esWo = w_dsWi + W786;
  unsigned short* w_dsWo = w_esWo + W262;
  unsigned short* w_effW1 = w_dsWo + W262;
  unsigned short* w_dffW1 = w_effW1 + W1M;
  unsigned short* w_effW2 = w_dffW1 + W1M;
  unsigned short* w_dffW2 = w_effW2 + W1M;
  unsigned short* actb = w_dffW2 + W1M;
  unsigned short* f_n_b = actb;
  unsigned short* dec_b = actb + 2 * U;
  unsigned short* tb_b = actb + 3 * U;
  unsigned short* Oec_b = actb + 4 * U;
  unsigned short* OaE = dec_b;  // reuse: dec_b dead after L3, tb_b after L5
  unsigned short* OaD = tb_b;
  unsigned short* QKVe_b = (unsigned short*)(ws + 0 * U);
  unsigned short* QKVd_b = (unsigned short*)(ws + 2 * U);
  unsigned short* He_b = (unsigned short*)(ws + 0 * U);
  unsigned short* Hd_b = (unsigned short*)(ws + 2 * U);

  const float* dc_Wv = dc_Wi + 1024 * 512;
  const float* dc_bv = dc_bi + 1024;
  const float* ec_Wq = ec_Wi;
  const float* ec_bq = ec_bi;
  const float* ec_Wk = ec_Wi + 512 * 512;
  const float* ec_bk = ec_bi + 512;
  const float* ec_Wv = ec_Wi + 1024 * 512;
  const float* ec_bv = ec_bi + 1024;

  auto J = [](const unsigned short* X, const unsigned short* W,
              const float* bias, const float* resid, float* Y,
              unsigned short* Ybf, float scale, int relu) {
    GemmJob j{};
    j.X = X; j.W = W; j.bias = bias; j.resid = resid;
    j.Y = Y; j.Ybf = Ybf; j.scale = scale; j.relu = relu;
    return j;
  };
  auto JF = [](const float* Xf, const float* As, const float* Aq,
               const float* g, const float* be, const unsigned short* W,
               const float* bias, unsigned short* Ybf, int relu) {
    GemmJob j{};
    j.Xf = Xf; j.Asum = As; j.Asq = Aq; j.g = g; j.be = be;
    j.W = W; j.bias = bias; j.Ybf = Ybf; j.scale = 1.f; j.relu = relu;
    return j;
  };

  // L1: Wf GEMM + LN(enc)+dec stats+cast + early casts + uvec(+bf) + zero
  {
    Phase0Args pa{};
    pa.enc = enc; pa.g_ec = n_ec_g; pa.b_ec = n_ec_b; pa.f_n = f_n_b;
    pa.dec = dec; pa.md = md; pa.q2d = q2d; pa.dec_b = dec_b;
    pa.cast[0] = {ec_Wq, w_ecWq, W262, nullptr};
    pa.cast[1] = {ec_Wk, w_ecWkg, W262, n_dci_g};
    pa.cast[2] = {ec_Wv, w_ecWvg, W262, n_dci_g};
    pa.cast[3] = {pW, w_pW, W262, nullptr};
    pa.Wk = ec_Wk; pa.Wv = ec_Wv; pa.bk = ec_bk; pa.bv = ec_bv;
    pa.g_dci = n_dci_g; pa.b_dci = n_dci_b;
    pa.u_k = u_k; pa.u_v = u_v; pa.c_k = c_k; pa.c_v = c_v;
    pa.WoA = dc_Wo; pa.WvA = dc_Wv; pa.Wfb = w_Wf;
    pa.bv2 = dc_bv; pa.bo2 = dc_bo; pa.bf_out = bf;
    pa.zbase = stx; pa.zcount = 10240;
    phase0<<<2497, 256, 0, stream>>>(pa);
  }
  // L2: batch A (5 GEMMs: t[stats], Qe, Kd, Vd, Ed) BM=128 + casts (z=5,6)
  {
    GemmBatch gb{};
    gb.j[0] = J(f_n_b, w_Wf, bf, nullptr, nullptr, tb_b, 1.f, 0);
    gb.j[0].Ssum = t_s; gb.j[0].Ssq = t_sq;
    gb.j[1] = J(f_n_b, w_ecWq, ec_bq, nullptr, nullptr, Qe_b, 0.125f, 0);
    gb.j[2] = J(dec_b, w_ecWkg, nullptr, nullptr, nullptr, Kd_b, 1.f, 0);
    gb.j[3] = J(dec_b, w_ecWvg, nullptr, nullptr, nullptr, Vd_b, 1.f, 0);
    gb.j[4] = J(dec_b, w_pW, pWb, nullptr, Ed, nullptr, 1.f, 0);
    int pg = 0;
    auto addpages = [&](const float* s, unsigned short* d, int n) {
      for (int off = 0; off < n; off += W262) {
        gb.cp[pg].src = s + off;
        gb.cp[pg].dst = d + off;
        ++pg;
      }
    };
    addpages(ec_Wo, w_ecWo, W262);
    addpages(es_Wi, w_esWi, W786);
    addpages(ds_Wi, w_dsWi, W786);
    addpages(es_Wo, w_esWo, W262);
    addpages(ds_Wo, w_dsWo, W262);
    addpages(eff_W1, w_effW1, W1M);
    addpages(dff_W1, w_dffW1, W1M);
    addpages(eff_W2, w_effW2, W1M);
    addpages(dff_W2, w_dffW2, W1M);
    gb.cast_total = pg * W262;  // 25 * 262144 = 6553600
    gemm_bf16<1, false, true, 8, 128><<<dim3(8, 8, 7), 512, 0, stream>>>(
        gb, 1024, 512, 512, 5);
  }
  // L3: batch B (Kt, Vt, Et) + mr (per-(j,i,b) LN stats via MFMA) at z==3
  {
    GemmBatch gb{};
    gb.j[0] = J(tb_b, w_ecWkg, nullptr, nullptr, nullptr, Kt_b, 1.f, 0);
    gb.j[1] = J(tb_b, w_ecWvg, nullptr, nullptr, nullptr, Vt_b, 1.f, 0);
    gb.j[2] = J(tb_b, w_pW, pb, nullptr, Et, nullptr, 1.f, 0);
    gb.mr = {dec_b, tb_b, md, q2d, t_s, t_sq, mArr, rArr};
    gemm_bf16<2, false, false, 4, 64><<<dim3(8, 16, 4), 256, 0, stream>>>(
        gb, 1024, 512, 512, 3);
  }
  // L4: ec cross-attention (256 blocks x 128 thr, j-split, hoisted loads)
  ec_attn<<<256, 128, 0, stream>>>(Qe_b, Kd_b, Kt_b, Vd_b, Vt_b, u_k, u_v, c_k,
                                   c_v, mArr, rArr, Oec_b);
  // L5: enc1 GEMM (z==0, with stats) + pooling (z=1..8 -> 1024 blocks)
  {
    GemmBatch gb{};
    gb.j[0] = J(Oec_b, w_ecWo, ec_bo, enc, enc1, nullptr, 1.f, 0);
    gb.j[0].Ssum = e1s; gb.j[0].Ssq = e1q;
    gb.pl = {Ed, Et, pv, dec, tb_b, dec1, d1s, d1q};
    gemm_bf16<3, false, true, 4, 64><<<dim3(8, 16, 9), 256, 0, stream>>>(
        gb, 1024, 512, 512, 1);
  }
  // L6: QKV projections with folded pre-norm (BM=128, NW=8)
  {
    GemmBatch gb{};
    gb.j[0] = JF(enc1, e1s, e1q, n_es_g, n_es_b, w_esWi, es_bi, QKVe_b, 0);
    gb.j[1] = JF(dec1, d1s, d1q, n_ds_g, n_ds_b, w_dsWi, ds_bi, QKVd_b, 0);
    gemm_bf16<0, true, false, 8, 128><<<dim3(24, 8, 2), 512, 0, stream>>>(
        gb, 1024, 1536, 512, -1);
  }
  // L7: self-attention cores (512 blocks x 128 thr, q-split)
  self_attn<<<dim3(128, 2, 2), 128, 0, stream>>>(QKVe_b, OaE, QKVd_b, OaD);
  // L8: output proj + residual + row stats (NW=8, BM=64)
  {
    GemmBatch gb{};
    gb.j[0] = J(OaE, w_esWo, es_bo, enc1, enc2, nullptr, 1.f, 0);
    gb.j[0].Ssum = e2s; gb.j[0].Ssq = e2q;
    gb.j[1] = J(OaD, w_dsWo, ds_bo, dec1, dec2, nullptr, 1.f, 0);
    gb.j[1].Ssum = d2s; gb.j[1].Ssq = d2q;
    gemm_bf16<0, false, true, 8, 64><<<dim3(8, 16, 2), 512, 0, stream>>>(
        gb, 1024, 512, 512, -1);
  }
  // L9: FFN layer 1 (relu) with folded pre-norm (BM=128, NW=8)
  {
    GemmBatch gb{};
    gb.j[0] = JF(enc2, e2s, e2q, n_ef_g, n_ef_b, w_effW1, eff_b1, He_b, 1);
    gb.j[1] = JF(dec2, d2s, d2q, n_df_g, n_df_b, w_dffW1, dff_b1, Hd_b, 1);
    gemm_bf16<0, true, false, 8, 128><<<dim3(32, 8, 2), 512, 0, stream>>>(
        gb, 1024, 2048, 512, -1);
  }
  // L10: FFN layer 2 + residual -> outputs (NW=8, BM=64)
  float* out = (float*)d_out;
  {
    GemmBatch gb{};
    gb.j[0] = J(He_b, w_effW2, eff_b2, enc2, out, nullptr, 1.f, 0);
    gb.j[1] = J(Hd_b, w_dffW2, dff_b2, dec2, out + U, nullptr, 1.f, 0);
    gemm_bf16<0, false, false, 8, 64><<<dim3(8, 16, 2), 512, 0, stream>>>(
        gb, 1024, 512, 2048, -1);
  }
}